// Round 1
// baseline (739.288 us; speedup 1.0000x reference)
//
#include <hip/hip_runtime.h>
#include <cmath>

// Problem constants: B=64, T=64, W=20, D=1024, K=4, STRIDE=4
// Conv lengths: 64 ->16 ->4 ->1 ; T_total = 21

// ---------------- weight transpose: wt[o][k*1024+i] = w[o][i*4+k] -------------
__global__ void transpose_w_kernel(const float* __restrict__ w, float* __restrict__ wt) {
    int idx = blockIdx.x * blockDim.x + threadIdx.x;   // 0 .. 1024*4096
    int i = idx & 1023;
    int k = (idx >> 10) & 3;
    int o = idx >> 12;
    wt[idx] = w[(o << 12) + (i << 2) + k];
}

// ---------------- NT GEMM: C[m,n] = sum_k A[m,k]*B[n,k] (+bias, relu) ---------
// tile 64x64, BK=16, 256 threads, 4x4 per thread. Optional split-K to CP slices.
// Row remap on direct store: row = (m/Tl)*rowstride + toff + m%Tl
template<bool SPLIT, bool RELU>
__global__ __launch_bounds__(256) void gemm_nt_kernel(
    const float* __restrict__ A, const float* __restrict__ Bm,
    const float* __restrict__ bias, float* __restrict__ C,
    int M, int N, int K, int Kchunk,
    int Tl, int rowstride, int toff, int ldc)
{
    __shared__ float As[16][64];
    __shared__ float Bs[16][64];
    const int tid = threadIdx.x;
    const int m0 = blockIdx.x * 64, n0 = blockIdx.y * 64;
    const int lm = tid & 63, lk = (tid >> 6) << 2;
    int k0 = 0, k1 = K;
    if (SPLIT) { k0 = blockIdx.z * Kchunk; k1 = k0 + Kchunk; }
    const float* Ap = A + (size_t)(m0 + lm) * K + lk;
    const float* Bp = Bm + (size_t)(n0 + lm) * K + lk;
    const int tx = tid & 15, ty = tid >> 4;
    float acc[4][4];
    #pragma unroll
    for (int a = 0; a < 4; a++)
        #pragma unroll
        for (int b = 0; b < 4; b++) acc[a][b] = 0.f;

    for (int k = k0; k < k1; k += 16) {
        float4 av = *(const float4*)(Ap + k);
        float4 bv = *(const float4*)(Bp + k);
        __syncthreads();
        As[lk+0][lm] = av.x; As[lk+1][lm] = av.y; As[lk+2][lm] = av.z; As[lk+3][lm] = av.w;
        Bs[lk+0][lm] = bv.x; Bs[lk+1][lm] = bv.y; Bs[lk+2][lm] = bv.z; Bs[lk+3][lm] = bv.w;
        __syncthreads();
        #pragma unroll
        for (int kk = 0; kk < 16; kk++) {
            float4 a4 = *(const float4*)&As[kk][ty << 2];
            float4 b4 = *(const float4*)&Bs[kk][tx << 2];
            acc[0][0] += a4.x*b4.x; acc[0][1] += a4.x*b4.y; acc[0][2] += a4.x*b4.z; acc[0][3] += a4.x*b4.w;
            acc[1][0] += a4.y*b4.x; acc[1][1] += a4.y*b4.y; acc[1][2] += a4.y*b4.z; acc[1][3] += a4.y*b4.w;
            acc[2][0] += a4.z*b4.x; acc[2][1] += a4.z*b4.y; acc[2][2] += a4.z*b4.z; acc[2][3] += a4.z*b4.w;
            acc[3][0] += a4.w*b4.x; acc[3][1] += a4.w*b4.y; acc[3][2] += a4.w*b4.z; acc[3][3] += a4.w*b4.w;
        }
    }

    if (SPLIT) {
        float* Cz = C + (size_t)blockIdx.z * M * N;
        #pragma unroll
        for (int im = 0; im < 4; im++) {
            int gm = m0 + (ty << 2) + im;
            float* r = Cz + (size_t)gm * N + n0 + (tx << 2);
            r[0] = acc[im][0]; r[1] = acc[im][1]; r[2] = acc[im][2]; r[3] = acc[im][3];
        }
    } else {
        #pragma unroll
        for (int im = 0; im < 4; im++) {
            int gm = m0 + (ty << 2) + im;
            int row = (gm / Tl) * rowstride + toff + (gm % Tl);
            float* r = C + (size_t)row * ldc + n0 + (tx << 2);
            #pragma unroll
            for (int in = 0; in < 4; in++) {
                float v = acc[im][in];
                if (bias) v += bias[n0 + (tx << 2) + in];
                if (RELU) v = fmaxf(v, 0.f);
                r[in] = v;
            }
        }
    }
}

// ---------------- split-K reduce + bias + relu + row remap --------------------
__global__ void epilogue_kernel(const float* __restrict__ CP_, int nz,
    const float* __restrict__ bias, float* __restrict__ D,
    int M, int N, int Tl, int rowstride, int toff, int ldc, int relu)
{
    int idx = blockIdx.x * 256 + threadIdx.x;
    if (idx >= M * N) return;
    int m = idx / N, n = idx - m * N;
    float s = 0.f;
    for (int z = 0; z < nz; z++) s += CP_[(size_t)z * M * N + idx];
    if (bias) s += bias[n];
    if (relu) s = fmaxf(s, 0.f);
    int row = (m / Tl) * rowstride + toff + (m % Tl);
    D[(size_t)row * ldc + n] = s;
}

// ---------------- per-row L2 norm (value only) --------------------------------
__global__ void rownorm_kernel(const float* __restrict__ X, float* __restrict__ nrm, int D) {
    int r = blockIdx.x;
    const float* x = X + (size_t)r * D;
    float s = 0.f;
    for (int d = threadIdx.x; d < D; d += blockDim.x) { float v = x[d]; s += v * v; }
    #pragma unroll
    for (int o = 32; o; o >>= 1) s += __shfl_xor(s, o, 64);
    __shared__ float red[4];
    if ((threadIdx.x & 63) == 0) red[threadIdx.x >> 6] = s;
    __syncthreads();
    if (threadIdx.x == 0) nrm[r] = sqrtf(red[0] + red[1] + red[2] + red[3]);
}

// ---------------- per-row L2 normalize ----------------------------------------
__global__ void l2normalize_kernel(const float* __restrict__ X, float* __restrict__ Y, int D) {
    int r = blockIdx.x;
    const float* x = X + (size_t)r * D;
    float s = 0.f;
    for (int d = threadIdx.x; d < D; d += blockDim.x) { float v = x[d]; s += v * v; }
    #pragma unroll
    for (int o = 32; o; o >>= 1) s += __shfl_xor(s, o, 64);
    __shared__ float red[4];
    __shared__ float tot;
    if ((threadIdx.x & 63) == 0) red[threadIdx.x >> 6] = s;
    __syncthreads();
    if (threadIdx.x == 0) tot = 1.0f / fmaxf(sqrtf(red[0] + red[1] + red[2] + red[3]), 1e-8f);
    __syncthreads();
    float inv = tot;
    float* y = Y + (size_t)r * D;
    for (int d = threadIdx.x; d < D; d += blockDim.x) y[d] = x[d] * inv;
}

// ---------------- Gram matrices: G[i][w][w'] = dot(words[i,w], words[i,w']) ---
__global__ void gram_kernel(const float* __restrict__ words, float* __restrict__ G) {
    int i = blockIdx.x;           // 64
    int pair = blockIdx.y;        // 400
    int w = pair / 20, w2 = pair % 20;
    int lane = threadIdx.x;       // 64
    const float* a = words + ((size_t)i * 20 + w) * 1024;
    const float* b = words + ((size_t)i * 20 + w2) * 1024;
    float s = 0.f;
    #pragma unroll
    for (int q = 0; q < 16; q++) { int d = lane + 64 * q; s += a[d] * b[d]; }
    #pragma unroll
    for (int o = 32; o; o >>= 1) s += __shfl_xor(s, o, 64);
    if (lane == 0) G[(size_t)i * 400 + pair] = s;
}

// ---------------- sim via logits + Gram quadratic form ------------------------
// One wave per (i,j,t). sim = (Σ p_w s_w / denom) / (max(||v||,eps)*max(sqrt(pᵀGp)/denom,eps))
__global__ void sim_kernel(const float* __restrict__ S_, const float* __restrict__ G_,
                           const float* __restrict__ VN_, const int* __restrict__ wmask,
                           float* __restrict__ SA_) {
    int item = blockIdx.x * 4 + (threadIdx.x >> 6);   // 0 .. 86016
    int lane = threadIdx.x & 63;
    int t = item % 21;
    int ij = item / 21;
    int j = ij & 63, i = ij >> 6;

    float s_raw = 0.f; bool act = false;
    if (lane < 20) {
        s_raw = S_[(size_t)(j * 21 + t) * 1280 + i * 20 + lane];
        act = (wmask[i * 20 + lane] != 0);
    }
    float s_m = act ? s_raw : -1e30f;
    float mx = s_m;
    #pragma unroll
    for (int o = 16; o; o >>= 1) mx = fmaxf(mx, __shfl_xor(mx, o, 32));
    float p = act ? __expf(s_m - mx) : 0.f;
    float denom = p, num = p * s_raw;
    #pragma unroll
    for (int o = 16; o; o >>= 1) { denom += __shfl_xor(denom, o, 32); num += __shfl_xor(num, o, 32); }

    const float* Gi = G_ + (size_t)i * 400;
    float c = 0.f;
    #pragma unroll
    for (int w = 0; w < 20; w++) {
        float pw = __shfl(p, w, 32);
        float gv = (lane < 20) ? Gi[w * 20 + lane] : 0.f;
        c += pw * gv;
    }
    float pc = p * c;
    #pragma unroll
    for (int o = 16; o; o >>= 1) pc += __shfl_xor(pc, o, 32);

    if (lane == 0) {
        float dot = num / denom;
        float vsn = sqrtf(fmaxf(pc, 0.f)) / denom;
        float nv = VN_[j * 21 + t];
        float sim = dot / (fmaxf(nv, 1e-8f) * fmaxf(vsn, 1e-8f));
        SA_[item] = sim;
    }
}

// ---------------- scores mean + positive_map ----------------------------------
__global__ void scores_kernel(const float* __restrict__ SA_, float* __restrict__ SC_,
                              float* __restrict__ out) {
    int idx = blockIdx.x * 256 + threadIdx.x;  // 4096 = i*64+j
    int i = idx >> 6, j = idx & 63;
    const float* row = SA_ + (size_t)idx * 21;
    float s = 0.f;
    #pragma unroll
    for (int t = 0; t < 21; t++) s += row[t];
    SC_[idx] = s * (1.0f / 21.0f);
    if (i == j) {
        #pragma unroll
        for (int t = 0; t < 21; t++) out[1 + i * 21 + t] = row[t];
    }
}

// ---------------- global-branch scores ----------------------------------------
__global__ void gscore_kernel(const float* __restrict__ SN_, const float* __restrict__ GN_,
                              float* __restrict__ GS_) {
    int item = blockIdx.x * 4 + (threadIdx.x >> 6);  // 4096
    int i = item >> 6, j = item & 63;
    int lane = threadIdx.x & 63;
    const float* a = SN_ + (size_t)i * 1024;
    const float* b = GN_ + (size_t)j * 1024;
    float s = 0.f;
    #pragma unroll
    for (int q = 0; q < 16; q++) { int d = lane + 64 * q; s += a[d] * b[d]; }
    #pragma unroll
    for (int o = 32; o; o >>= 1) s += __shfl_xor(s, o, 64);
    if (lane == 0) GS_[item] = s;
}

// ---------------- margin ranking loss over both score matrices ----------------
__global__ void loss_kernel(const float* __restrict__ SC_, const float* __restrict__ GS_,
                            float* __restrict__ out) {
    __shared__ float d1[64], d2[64], red[4];
    int tid = threadIdx.x;
    if (tid < 64) { d1[tid] = SC_[tid * 65]; d2[tid] = GS_[tid * 65]; }
    __syncthreads();
    float acc = 0.f;
    for (int idx = tid; idx < 4096; idx += 256) {
        int i = idx >> 6, j = idx & 63;
        if (i != j) {
            float s = SC_[idx];
            acc += fmaxf(0.2f + s - d1[i], 0.f) + fmaxf(0.2f + s - d1[j], 0.f);
            float g = GS_[idx];
            acc += fmaxf(0.2f + g - d2[i], 0.f) + fmaxf(0.2f + g - d2[j], 0.f);
        }
    }
    #pragma unroll
    for (int o = 32; o; o >>= 1) acc += __shfl_xor(acc, o, 64);
    if ((tid & 63) == 0) red[tid >> 6] = acc;
    __syncthreads();
    if (tid == 0) out[0] = (red[0] + red[1] + red[2] + red[3]) * (1.0f / 64.0f);
}

// ------------------------------------------------------------------------------
extern "C" void kernel_launch(void* const* d_in, const int* in_sizes, int n_in,
                              void* d_out, int out_size, void* d_ws, size_t ws_size,
                              hipStream_t stream)
{
    const float* video     = (const float*)d_in[0];
    const float* words     = (const float*)d_in[1];
    const int*   w_masks   = (const int*)  d_in[2];
    const float* sentences = (const float*)d_in[3];
    const float* conv0_w   = (const float*)d_in[4];
    const float* conv0_b   = (const float*)d_in[5];
    const float* conv1_w   = (const float*)d_in[6];
    const float* conv1_b   = (const float*)d_in[7];
    const float* conv2_w   = (const float*)d_in[8];
    const float* conv2_b   = (const float*)d_in[9];
    const float* conv1d_w  = (const float*)d_in[10];
    const float* conv1d_b  = (const float*)d_in[11];
    const float* fc_w      = (const float*)d_in[12];
    const float* fc_b      = (const float*)d_in[13];
    float* out = (float*)d_out;
    float* ws = (float*)d_ws;

    // workspace layout (floats); WT (4.19M) and S (1.72M) share: WT dead before S written
    float* WT = ws + 0;
    float* Sb = ws + 0;
    float* A1 = ws + 4194304;   // (64,16,1024) post-relu conv0, (B,L,C)
    float* A2 = ws + 5242880;   // (64,4,1024)
    float* A3 = ws + 5505024;   // (64,1,1024)
    float* VC = ws + 5570560;   // v_cat (1344,1024), row = j*21+t
    float* CP = ws + 6946816;   // split-K partials, up to 1,048,576 floats
    float* VN = ws + 7995392;   // 1344 row norms
    float* GR = ws + 7996736;   // 64 x 20 x 20 Gram
    float* SA = ws + 8022336;   // score_all (64,64,21)
    float* SC = ws + 8108352;   // scores (64,64)
    float* GV = ws + 8112448;   // fc output (64,1024)
    float* GN = ws + 8177984;   // normalized g_v
    float* SN = ws + 8243520;   // normalized sentences
    float* GS = ws + 8309056;   // g_scores (64,64)

    dim3 blk(256);

    // conv0: (B*T,4096) x (1024,4096)^T -> A1, relu.  M=1024 N=1024 K=4096
    transpose_w_kernel<<<16384, blk, 0, stream>>>(conv0_w, WT);
    gemm_nt_kernel<false,true><<<dim3(16,16,1), blk, 0, stream>>>(
        video, WT, conv0_b, A1, 1024, 1024, 4096, 0, 1, 1, 0, 1024);

    // conv1: M=256 -> split-K x4
    transpose_w_kernel<<<16384, blk, 0, stream>>>(conv1_w, WT);
    gemm_nt_kernel<true,false><<<dim3(4,16,4), blk, 0, stream>>>(
        A1, WT, nullptr, CP, 256, 1024, 4096, 1024, 0, 0, 0, 0);
    epilogue_kernel<<<1024, blk, 0, stream>>>(CP, 4, conv1_b, A2, 256, 1024, 1, 1, 0, 1024, 1);

    // conv2: M=64 -> split-K x16
    transpose_w_kernel<<<16384, blk, 0, stream>>>(conv2_w, WT);
    gemm_nt_kernel<true,false><<<dim3(1,16,16), blk, 0, stream>>>(
        A2, WT, nullptr, CP, 64, 1024, 4096, 256, 0, 0, 0, 0);
    epilogue_kernel<<<256, blk, 0, stream>>>(CP, 16, conv2_b, A3, 64, 1024, 1, 1, 0, 1024, 1);

    // conv1d level0 -> VC rows j*21 + t (t<16)
    gemm_nt_kernel<false,false><<<dim3(16,16,1), blk, 0, stream>>>(
        A1, conv1d_w, conv1d_b, VC, 1024, 1024, 1024, 0, 16, 21, 0, 1024);
    // level1 -> rows j*21 + 16 + t
    gemm_nt_kernel<true,false><<<dim3(4,16,4), blk, 0, stream>>>(
        A2, conv1d_w, nullptr, CP, 256, 1024, 1024, 256, 0, 0, 0, 0);
    epilogue_kernel<<<1024, blk, 0, stream>>>(CP, 4, conv1d_b, VC, 256, 1024, 4, 21, 16, 1024, 0);
    // level2 -> rows j*21 + 20
    gemm_nt_kernel<true,false><<<dim3(1,16,8), blk, 0, stream>>>(
        A3, conv1d_w, nullptr, CP, 64, 1024, 1024, 128, 0, 0, 0, 0);
    epilogue_kernel<<<256, blk, 0, stream>>>(CP, 8, conv1d_b, VC, 64, 1024, 1, 21, 20, 1024, 0);

    // fc: g = A3 @ fc_w^T + fc_b
    gemm_nt_kernel<true,false><<<dim3(1,16,8), blk, 0, stream>>>(
        A3, fc_w, nullptr, CP, 64, 1024, 1024, 128, 0, 0, 0, 0);
    epilogue_kernel<<<256, blk, 0, stream>>>(CP, 8, fc_b, GV, 64, 1024, 1, 1, 0, 1024, 0);

    // attention logits: S[(j,t),(i,w)] = VC . words^T   M=1344 N=1280 K=1024
    gemm_nt_kernel<false,false><<<dim3(21,20,1), blk, 0, stream>>>(
        VC, words, nullptr, Sb, 1344, 1280, 1024, 0, 1, 1, 0, 1280);

    rownorm_kernel<<<1344, blk, 0, stream>>>(VC, VN, 1024);
    gram_kernel<<<dim3(64,400), dim3(64), 0, stream>>>(words, GR);
    sim_kernel<<<21504, blk, 0, stream>>>(Sb, GR, VN, w_masks, SA);
    scores_kernel<<<16, blk, 0, stream>>>(SA, SC, out);

    l2normalize_kernel<<<64, blk, 0, stream>>>(GV, GN, 1024);
    l2normalize_kernel<<<64, blk, 0, stream>>>(sentences, SN, 1024);
    gscore_kernel<<<1024, blk, 0, stream>>>(SN, GN, GS);
    loss_kernel<<<1, blk, 0, stream>>>(SC, GS, out);
}

// Round 2
// 373.198 us; speedup vs baseline: 1.9810x; 1.9810x over previous
//
#include <hip/hip_runtime.h>
#include <cmath>
#include <cstdint>

// B=64, T=64, W=20, D=1024, K=4, STRIDE=4 ; conv lengths 64->16->4->1 ; T_total=21

typedef __bf16 bf16_t;
typedef bf16_t bf16x8 __attribute__((ext_vector_type(8)));
typedef bf16_t bf16x4 __attribute__((ext_vector_type(4)));
typedef float  f32x4  __attribute__((ext_vector_type(4)));

__device__ __forceinline__ void gload_lds16(const void* g, void* l) {
    __builtin_amdgcn_global_load_lds(
        (const __attribute__((address_space(1))) void*)g,
        (__attribute__((address_space(3))) void*)l, 16, 0, 0);
}

// ---------------- fp32 -> bf16 cast, 4 elems/thread ---------------------------
__global__ void cast4_kernel(const float* __restrict__ x, bf16_t* __restrict__ y) {
    int idx = blockIdx.x * 256 + threadIdx.x;
    float4 v = ((const float4*)x)[idx];
    bf16x4 o = { (bf16_t)v.x, (bf16_t)v.y, (bf16_t)v.z, (bf16_t)v.w };
    ((bf16x4*)y)[idx] = o;
}

// ---- weight transpose+cast: wt[o][k*1024+i] = (bf16) w[o][i*4+k] -------------
__global__ void transpose_cast_kernel(const float* __restrict__ w, bf16_t* __restrict__ wt) {
    int idx = blockIdx.x * 256 + threadIdx.x;   // 0 .. 4194304
    int i = idx & 1023;
    int k = (idx >> 10) & 3;
    int o = idx >> 12;
    wt[idx] = (bf16_t)w[(o << 12) + (i << 2) + k];
}

// ---------------- bf16 MFMA NT GEMM: C[m,n] = sum_k A[m,k]*B[n,k] -------------
// 64x64 tile, BK=64, 256 threads (4 waves, each 32x32 quadrant of 2x2 mfma).
// global_load_lds width-16 staging. Optional split-K -> fp32 partials.
// Direct store: row = (m/Tl)*rowstride + toff + m%Tl, +bias, relu, bf16/f32 out.
template<bool SPLIT, bool RELU, bool OUTBF16>
__global__ __launch_bounds__(256) void mgemm_kernel(
    const bf16_t* __restrict__ A, const bf16_t* __restrict__ B,
    const float* __restrict__ bias, void* __restrict__ C,
    int M, int N, int K, int Kchunk,
    int Tl, int rowstride, int toff, int ldc)
{
    __shared__ __align__(16) bf16_t sA[64 * 64];
    __shared__ __align__(16) bf16_t sB[64 * 64];
    const int tid  = threadIdx.x;
    const int lane = tid & 63;
    const int wave = tid >> 6;
    const int m0 = blockIdx.x * 64, n0 = blockIdx.y * 64;
    int k0 = 0, kend = K;
    if (SPLIT) { k0 = blockIdx.z * Kchunk; kend = k0 + Kchunk; }

    // staging: thread t loads 16B = row (t>>3), col8 (t&7); issue1 = rows+32
    const bf16_t* Ag = A + (size_t)(m0 + (tid >> 3)) * K + (tid & 7) * 8;
    const bf16_t* Bg = B + (size_t)(n0 + (tid >> 3)) * K + (tid & 7) * 8;
    bf16_t* lA0 = sA + tid * 8;           bf16_t* lA1 = sA + 2048 + tid * 8;
    bf16_t* lB0 = sB + tid * 8;           bf16_t* lB1 = sB + 2048 + tid * 8;
    const size_t rowskip = (size_t)32 * K;

    const int wr = (wave >> 1) * 32;      // quadrant row offset
    const int wc = (wave & 1) * 32;       // quadrant col offset
    const int fm = lane & 15;             // fragment row/col within 16
    const int fk = (lane >> 4) * 8;       // fragment k offset

    f32x4 acc[2][2];
    #pragma unroll
    for (int a = 0; a < 2; a++)
        #pragma unroll
        for (int b = 0; b < 2; b++) acc[a][b] = (f32x4){0.f, 0.f, 0.f, 0.f};

    for (int k = k0; k < kend; k += 64) {
        __syncthreads();                  // previous iter's LDS reads done
        gload_lds16(Ag + k,            lA0);
        gload_lds16(Ag + k + rowskip,  lA1);
        gload_lds16(Bg + k,            lB0);
        gload_lds16(Bg + k + rowskip,  lB1);
        __syncthreads();                  // drains vmcnt(0): staging complete
        #pragma unroll
        for (int ks = 0; ks < 64; ks += 32) {
            bf16x8 a0 = *(const bf16x8*)&sA[(wr +      fm) * 64 + ks + fk];
            bf16x8 a1 = *(const bf16x8*)&sA[(wr + 16 + fm) * 64 + ks + fk];
            bf16x8 b0 = *(const bf16x8*)&sB[(wc +      fm) * 64 + ks + fk];
            bf16x8 b1 = *(const bf16x8*)&sB[(wc + 16 + fm) * 64 + ks + fk];
            acc[0][0] = __builtin_amdgcn_mfma_f32_16x16x32_bf16(a0, b0, acc[0][0], 0, 0, 0);
            acc[0][1] = __builtin_amdgcn_mfma_f32_16x16x32_bf16(a0, b1, acc[0][1], 0, 0, 0);
            acc[1][0] = __builtin_amdgcn_mfma_f32_16x16x32_bf16(a1, b0, acc[1][0], 0, 0, 0);
            acc[1][1] = __builtin_amdgcn_mfma_f32_16x16x32_bf16(a1, b1, acc[1][1], 0, 0, 0);
        }
    }

    // C/D layout: col = lane&15, row = (lane>>4)*4 + reg   [verified m89/m91]
    if (SPLIT) {
        float* Cz = (float*)C + (size_t)blockIdx.z * M * N;
        #pragma unroll
        for (int im = 0; im < 2; im++)
            #pragma unroll
            for (int rr = 0; rr < 4; rr++) {
                int gm = m0 + wr + im * 16 + (lane >> 4) * 4 + rr;
                #pragma unroll
                for (int in_ = 0; in_ < 2; in_++) {
                    int cg = n0 + wc + in_ * 16 + (lane & 15);
                    Cz[(size_t)gm * N + cg] = acc[im][in_][rr];
                }
            }
    } else {
        #pragma unroll
        for (int im = 0; im < 2; im++)
            #pragma unroll
            for (int rr = 0; rr < 4; rr++) {
                int gm = m0 + wr + im * 16 + (lane >> 4) * 4 + rr;
                int row = (gm / Tl) * rowstride + toff + gm % Tl;
                #pragma unroll
                for (int in_ = 0; in_ < 2; in_++) {
                    int cg = n0 + wc + in_ * 16 + (lane & 15);
                    float v = acc[im][in_][rr];
                    if (bias) v += bias[cg];
                    if (RELU) v = fmaxf(v, 0.f);
                    if (OUTBF16) ((bf16_t*)C)[(size_t)row * ldc + cg] = (bf16_t)v;
                    else         ((float*)C)[(size_t)row * ldc + cg] = v;
                }
            }
    }
}

// ------- split-K reduce + bias + relu + row remap -> bf16 (and opt fp32) ------
__global__ void epilogueB_kernel(const float* __restrict__ CP_, int nz,
    const float* __restrict__ bias, bf16_t* __restrict__ D, float* __restrict__ D2,
    int M, int N, int Tl, int rowstride, int toff, int ldc, int relu)
{
    int idx = blockIdx.x * 256 + threadIdx.x;
    if (idx >= M * N) return;
    int m = idx / N, n = idx - m * N;
    float s = 0.f;
    for (int z = 0; z < nz; z++) s += CP_[(size_t)z * M * N + idx];
    if (bias) s += bias[n];
    if (relu) s = fmaxf(s, 0.f);
    int row = (m / Tl) * rowstride + toff + (m % Tl);
    D[(size_t)row * ldc + n] = (bf16_t)s;
    if (D2) D2[idx] = s;
}

// ---------------- fp32 NT GEMM (kept for tiny fc matmul) ----------------------
template<bool SPLIT, bool RELU>
__global__ __launch_bounds__(256) void gemm_nt_kernel(
    const float* __restrict__ A, const float* __restrict__ Bm,
    const float* __restrict__ bias, float* __restrict__ C,
    int M, int N, int K, int Kchunk,
    int Tl, int rowstride, int toff, int ldc)
{
    __shared__ float As[16][64];
    __shared__ float Bs[16][64];
    const int tid = threadIdx.x;
    const int m0 = blockIdx.x * 64, n0 = blockIdx.y * 64;
    const int lm = tid & 63, lk = (tid >> 6) << 2;
    int k0 = 0, k1 = K;
    if (SPLIT) { k0 = blockIdx.z * Kchunk; k1 = k0 + Kchunk; }
    const float* Ap = A + (size_t)(m0 + lm) * K + lk;
    const float* Bp = Bm + (size_t)(n0 + lm) * K + lk;
    const int tx = tid & 15, ty = tid >> 4;
    float acc[4][4];
    #pragma unroll
    for (int a = 0; a < 4; a++)
        #pragma unroll
        for (int b = 0; b < 4; b++) acc[a][b] = 0.f;

    for (int k = k0; k < k1; k += 16) {
        float4 av = *(const float4*)(Ap + k);
        float4 bv = *(const float4*)(Bp + k);
        __syncthreads();
        As[lk+0][lm] = av.x; As[lk+1][lm] = av.y; As[lk+2][lm] = av.z; As[lk+3][lm] = av.w;
        Bs[lk+0][lm] = bv.x; Bs[lk+1][lm] = bv.y; Bs[lk+2][lm] = bv.z; Bs[lk+3][lm] = bv.w;
        __syncthreads();
        #pragma unroll
        for (int kk = 0; kk < 16; kk++) {
            float4 a4 = *(const float4*)&As[kk][ty << 2];
            float4 b4 = *(const float4*)&Bs[kk][tx << 2];
            acc[0][0] += a4.x*b4.x; acc[0][1] += a4.x*b4.y; acc[0][2] += a4.x*b4.z; acc[0][3] += a4.x*b4.w;
            acc[1][0] += a4.y*b4.x; acc[1][1] += a4.y*b4.y; acc[1][2] += a4.y*b4.z; acc[1][3] += a4.y*b4.w;
            acc[2][0] += a4.z*b4.x; acc[2][1] += a4.z*b4.y; acc[2][2] += a4.z*b4.z; acc[2][3] += a4.z*b4.w;
            acc[3][0] += a4.w*b4.x; acc[3][1] += a4.w*b4.y; acc[3][2] += a4.w*b4.z; acc[3][3] += a4.w*b4.w;
        }
    }

    if (SPLIT) {
        float* Cz = C + (size_t)blockIdx.z * M * N;
        #pragma unroll
        for (int im = 0; im < 4; im++) {
            int gm = m0 + (ty << 2) + im;
            float* r = Cz + (size_t)gm * N + n0 + (tx << 2);
            r[0] = acc[im][0]; r[1] = acc[im][1]; r[2] = acc[im][2]; r[3] = acc[im][3];
        }
    } else {
        #pragma unroll
        for (int im = 0; im < 4; im++) {
            int gm = m0 + (ty << 2) + im;
            int row = (gm / Tl) * rowstride + toff + (gm % Tl);
            float* r = C + (size_t)row * ldc + n0 + (tx << 2);
            #pragma unroll
            for (int in = 0; in < 4; in++) {
                float v = acc[im][in];
                if (bias) v += bias[n0 + (tx << 2) + in];
                if (RELU) v = fmaxf(v, 0.f);
                r[in] = v;
            }
        }
    }
}

__global__ void epilogue_kernel(const float* __restrict__ CP_, int nz,
    const float* __restrict__ bias, float* __restrict__ D,
    int M, int N, int Tl, int rowstride, int toff, int ldc, int relu)
{
    int idx = blockIdx.x * 256 + threadIdx.x;
    if (idx >= M * N) return;
    int m = idx / N, n = idx - m * N;
    float s = 0.f;
    for (int z = 0; z < nz; z++) s += CP_[(size_t)z * M * N + idx];
    if (bias) s += bias[n];
    if (relu) s = fmaxf(s, 0.f);
    int row = (m / Tl) * rowstride + toff + (m % Tl);
    D[(size_t)row * ldc + n] = s;
}

// ---------------- per-row L2 norm of bf16 rows (value only) -------------------
__global__ void rownorm_kernel(const bf16_t* __restrict__ X, float* __restrict__ nrm, int D) {
    int r = blockIdx.x;
    const bf16_t* x = X + (size_t)r * D;
    float s = 0.f;
    for (int d = threadIdx.x; d < D; d += blockDim.x) { float v = (float)x[d]; s += v * v; }
    #pragma unroll
    for (int o = 32; o; o >>= 1) s += __shfl_xor(s, o, 64);
    __shared__ float red[4];
    if ((threadIdx.x & 63) == 0) red[threadIdx.x >> 6] = s;
    __syncthreads();
    if (threadIdx.x == 0) nrm[r] = sqrtf(red[0] + red[1] + red[2] + red[3]);
}

// ---------------- per-row L2 normalize (fp32) ---------------------------------
__global__ void l2normalize_kernel(const float* __restrict__ X, float* __restrict__ Y, int D) {
    int r = blockIdx.x;
    const float* x = X + (size_t)r * D;
    float s = 0.f;
    for (int d = threadIdx.x; d < D; d += blockDim.x) { float v = x[d]; s += v * v; }
    #pragma unroll
    for (int o = 32; o; o >>= 1) s += __shfl_xor(s, o, 64);
    __shared__ float red[4];
    __shared__ float tot;
    if ((threadIdx.x & 63) == 0) red[threadIdx.x >> 6] = s;
    __syncthreads();
    if (threadIdx.x == 0) tot = 1.0f / fmaxf(sqrtf(red[0] + red[1] + red[2] + red[3]), 1e-8f);
    __syncthreads();
    float inv = tot;
    float* y = Y + (size_t)r * D;
    for (int d = threadIdx.x; d < D; d += blockDim.x) y[d] = x[d] * inv;
}

// ---------------- Gram: G[i][w][w'] = dot(words[i,w], words[i,w']) ------------
__global__ void gram_kernel(const float* __restrict__ words, float* __restrict__ G) {
    int i = blockIdx.x;                       // 64
    int wave = threadIdx.x >> 6;
    int lane = threadIdx.x & 63;
    int pair = blockIdx.y * 4 + wave;         // 0..399
    int w = pair / 20, w2 = pair % 20;
    const float* a = words + ((size_t)i * 20 + w) * 1024;
    const float* b = words + ((size_t)i * 20 + w2) * 1024;
    float s = 0.f;
    #pragma unroll
    for (int q = 0; q < 16; q++) { int d = lane + 64 * q; s += a[d] * b[d]; }
    #pragma unroll
    for (int o = 32; o; o >>= 1) s += __shfl_xor(s, o, 64);
    if (lane == 0) G[(size_t)i * 400 + pair] = s;
}

// ---------------- sim via logits + Gram quadratic form ------------------------
__global__ void sim_kernel(const float* __restrict__ S_, const float* __restrict__ G_,
                           const float* __restrict__ VN_, const int* __restrict__ wmask,
                           float* __restrict__ SA_) {
    int item = blockIdx.x * 4 + (threadIdx.x >> 6);   // 0 .. 86016
    int lane = threadIdx.x & 63;
    int t = item % 21;
    int ij = item / 21;
    int j = ij & 63, i = ij >> 6;

    float s_raw = 0.f; bool act = false;
    if (lane < 20) {
        s_raw = S_[(size_t)(j * 21 + t) * 1280 + i * 20 + lane];
        act = (wmask[i * 20 + lane] != 0);
    }
    float s_m = act ? s_raw : -1e30f;
    float mx = s_m;
    #pragma unroll
    for (int o = 16; o; o >>= 1) mx = fmaxf(mx, __shfl_xor(mx, o, 32));
    float p = act ? __expf(s_m - mx) : 0.f;
    float denom = p, num = p * s_raw;
    #pragma unroll
    for (int o = 16; o; o >>= 1) { denom += __shfl_xor(denom, o, 32); num += __shfl_xor(num, o, 32); }

    const float* Gi = G_ + (size_t)i * 400;
    float c = 0.f;
    #pragma unroll
    for (int w = 0; w < 20; w++) {
        float pw = __shfl(p, w, 32);
        float gv = (lane < 20) ? Gi[w * 20 + lane] : 0.f;
        c += pw * gv;
    }
    float pc = p * c;
    #pragma unroll
    for (int o = 16; o; o >>= 1) pc += __shfl_xor(pc, o, 32);

    if (lane == 0) {
        float dot = num / denom;
        float vsn = sqrtf(fmaxf(pc, 0.f)) / denom;
        float nv = VN_[j * 21 + t];
        float sim = dot / (fmaxf(nv, 1e-8f) * fmaxf(vsn, 1e-8f));
        SA_[item] = sim;
    }
}

// ---------------- scores mean + positive_map ----------------------------------
__global__ void scores_kernel(const float* __restrict__ SA_, float* __restrict__ SC_,
                              float* __restrict__ out) {
    int idx = blockIdx.x * 256 + threadIdx.x;  // 4096 = i*64+j
    int i = idx >> 6, j = idx & 63;
    const float* row = SA_ + (size_t)idx * 21;
    float s = 0.f;
    #pragma unroll
    for (int t = 0; t < 21; t++) s += row[t];
    SC_[idx] = s * (1.0f / 21.0f);
    if (i == j) {
        #pragma unroll
        for (int t = 0; t < 21; t++) out[1 + i * 21 + t] = row[t];
    }
}

// ---------------- global-branch scores ----------------------------------------
__global__ void gscore_kernel(const float* __restrict__ SN_, const float* __restrict__ GN_,
                              float* __restrict__ GS_) {
    int item = blockIdx.x * 4 + (threadIdx.x >> 6);  // 4096
    int i = item >> 6, j = item & 63;
    int lane = threadIdx.x & 63;
    const float* a = SN_ + (size_t)i * 1024;
    const float* b = GN_ + (size_t)j * 1024;
    float s = 0.f;
    #pragma unroll
    for (int q = 0; q < 16; q++) { int d = lane + 64 * q; s += a[d] * b[d]; }
    #pragma unroll
    for (int o = 32; o; o >>= 1) s += __shfl_xor(s, o, 64);
    if (lane == 0) GS_[item] = s;
}

// ---------------- margin ranking loss -----------------------------------------
__global__ void loss_kernel(const float* __restrict__ SC_, const float* __restrict__ GS_,
                            float* __restrict__ out) {
    __shared__ float d1[64], d2[64], red[4];
    int tid = threadIdx.x;
    if (tid < 64) { d1[tid] = SC_[tid * 65]; d2[tid] = GS_[tid * 65]; }
    __syncthreads();
    float acc = 0.f;
    for (int idx = tid; idx < 4096; idx += 256) {
        int i = idx >> 6, j = idx & 63;
        if (i != j) {
            float s = SC_[idx];
            acc += fmaxf(0.2f + s - d1[i], 0.f) + fmaxf(0.2f + s - d1[j], 0.f);
            float g = GS_[idx];
            acc += fmaxf(0.2f + g - d2[i], 0.f) + fmaxf(0.2f + g - d2[j], 0.f);
        }
    }
    #pragma unroll
    for (int o = 32; o; o >>= 1) acc += __shfl_xor(acc, o, 64);
    if ((tid & 63) == 0) red[tid >> 6] = acc;
    __syncthreads();
    if (tid == 0) out[0] = (red[0] + red[1] + red[2] + red[3]) * (1.0f / 64.0f);
}

// ------------------------------------------------------------------------------
extern "C" void kernel_launch(void* const* d_in, const int* in_sizes, int n_in,
                              void* d_out, int out_size, void* d_ws, size_t ws_size,
                              hipStream_t stream)
{
    const float* video     = (const float*)d_in[0];
    const float* words     = (const float*)d_in[1];
    const int*   w_masks   = (const int*)  d_in[2];
    const float* sentences = (const float*)d_in[3];
    const float* conv0_w   = (const float*)d_in[4];
    const float* conv0_b   = (const float*)d_in[5];
    const float* conv1_w   = (const float*)d_in[6];
    const float* conv1_b   = (const float*)d_in[7];
    const float* conv2_w   = (const float*)d_in[8];
    const float* conv2_b   = (const float*)d_in[9];
    const float* conv1d_w  = (const float*)d_in[10];
    const float* conv1d_b  = (const float*)d_in[11];
    const float* fc_w      = (const float*)d_in[12];
    const float* fc_b      = (const float*)d_in[13];
    float* out = (float*)d_out;
    float* ws = (float*)d_ws;

    // workspace layout (float units). WTb (bf16 weights) aliases Sb (logits):
    // WTb dead after conv2 GEMM, Sb written by attention GEMM afterwards.
    bf16_t* WTb = (bf16_t*)(ws + 0);            // 4,194,304 bf16
    float*  Sb  = ws + 0;                       // 1,720,320 fp32 (alias)
    bf16_t* Vb  = (bf16_t*)(ws + 2097152);      // 4,194,304 bf16
    float*  CP  = ws + 4194304;                 // 1,048,576 fp32 partials
    bf16_t* A1b = (bf16_t*)(ws + 5242880);      // 1,048,576 bf16
    bf16_t* A2b = (bf16_t*)(ws + 5767168);      //   262,144 bf16
    bf16_t* A3b = (bf16_t*)(ws + 5898240);      //    65,536 bf16
    float*  A3f = ws + 5931008;                 //    65,536 fp32
    bf16_t* VCb = (bf16_t*)(ws + 5996544);      // 1,376,256 bf16
    bf16_t* Wb  = (bf16_t*)(ws + 6684672);      // 1,310,720 bf16
    bf16_t* C1b = (bf16_t*)(ws + 7340032);      // 1,048,576 bf16
    float*  VN  = ws + 7864320;                 // 1,344
    float*  GR  = ws + 7865664;                 // 25,600
    float*  SA  = ws + 7891264;                 // 86,016
    float*  SC  = ws + 7977280;                 // 4,096
    float*  GV  = ws + 7981376;                 // 65,536
    float*  GN  = ws + 8046912;                 // 65,536
    float*  SN  = ws + 8112448;                 // 65,536
    float*  GS  = ws + 8177984;                 // 4,096

    dim3 blk(256);

    // casts
    cast4_kernel<<<4096, blk, 0, stream>>>(video, Vb);        // 4,194,304
    cast4_kernel<<<1280, blk, 0, stream>>>(words, Wb);        // 1,310,720
    cast4_kernel<<<1024, blk, 0, stream>>>(conv1d_w, C1b);    // 1,048,576

    // conv0: (1024,4096)x(1024,4096)^T, relu -> A1b
    transpose_cast_kernel<<<16384, blk, 0, stream>>>(conv0_w, WTb);
    mgemm_kernel<false,true,true><<<dim3(16,16,1), blk, 0, stream>>>(
        Vb, WTb, conv0_b, A1b, 1024, 1024, 4096, 0, 1, 1, 0, 1024);

    // conv1: M=256, split-K x4
    transpose_cast_kernel<<<16384, blk, 0, stream>>>(conv1_w, WTb);
    mgemm_kernel<true,false,false><<<dim3(4,16,4), blk, 0, stream>>>(
        A1b, WTb, nullptr, CP, 256, 1024, 4096, 1024, 0, 0, 0, 0);
    epilogueB_kernel<<<1024, blk, 0, stream>>>(CP, 4, conv1_b, A2b, nullptr,
        256, 1024, 1, 1, 0, 1024, 1);

    // conv2: M=64, split-K x16 -> A3b (bf16) + A3f (fp32 for fc)
    transpose_cast_kernel<<<16384, blk, 0, stream>>>(conv2_w, WTb);
    mgemm_kernel<true,false,false><<<dim3(1,16,16), blk, 0, stream>>>(
        A2b, WTb, nullptr, CP, 64, 1024, 4096, 256, 0, 0, 0, 0);
    epilogueB_kernel<<<256, blk, 0, stream>>>(CP, 16, conv2_b, A3b, A3f,
        64, 1024, 1, 1, 0, 1024, 1);

    // conv1d level0 -> VCb rows j*21+t (t<16)
    mgemm_kernel<false,false,true><<<dim3(16,16,1), blk, 0, stream>>>(
        A1b, C1b, conv1d_b, VCb, 1024, 1024, 1024, 0, 16, 21, 0, 1024);
    // level1 -> rows j*21+16+t
    mgemm_kernel<true,false,false><<<dim3(4,16,4), blk, 0, stream>>>(
        A2b, C1b, nullptr, CP, 256, 1024, 1024, 256, 0, 0, 0, 0);
    epilogueB_kernel<<<1024, blk, 0, stream>>>(CP, 4, conv1d_b, VCb, nullptr,
        256, 1024, 4, 21, 16, 1024, 0);
    // level2 -> rows j*21+20
    mgemm_kernel<true,false,false><<<dim3(1,16,8), blk, 0, stream>>>(
        A3b, C1b, nullptr, CP, 64, 1024, 1024, 128, 0, 0, 0, 0);
    epilogueB_kernel<<<256, blk, 0, stream>>>(CP, 8, conv1d_b, VCb, nullptr,
        64, 1024, 1, 21, 20, 1024, 0);

    // fc (fp32, tiny): g = A3f @ fc_w^T + fc_b
    gemm_nt_kernel<true,false><<<dim3(1,16,8), blk, 0, stream>>>(
        A3f, fc_w, nullptr, CP, 64, 1024, 1024, 128, 0, 0, 0, 0);
    epilogue_kernel<<<256, blk, 0, stream>>>(CP, 8, fc_b, GV, 64, 1024, 1, 1, 0, 1024, 0);

    // attention logits: Sb[(j,t),(i,w)] = VCb . Wb^T  (M=1344,N=1280,K=1024) fp32 out
    mgemm_kernel<false,false,false><<<dim3(21,20,1), blk, 0, stream>>>(
        VCb, Wb, nullptr, Sb, 1344, 1280, 1024, 0, 1, 1, 0, 1280);

    rownorm_kernel<<<1344, blk, 0, stream>>>(VCb, VN, 1024);
    gram_kernel<<<dim3(64,100), blk, 0, stream>>>(words, GR);
    sim_kernel<<<21504, blk, 0, stream>>>(Sb, GR, VN, w_masks, SA);
    scores_kernel<<<16, blk, 0, stream>>>(SA, SC, out);

    l2normalize_kernel<<<64, blk, 0, stream>>>(GV, GN, 1024);
    l2normalize_kernel<<<64, blk, 0, stream>>>(sentences, SN, 1024);
    gscore_kernel<<<1024, blk, 0, stream>>>(SN, GN, GS);
    loss_kernel<<<1, blk, 0, stream>>>(SC, GS, out);
}

// Round 3
// 323.462 us; speedup vs baseline: 2.2856x; 1.1538x over previous
//
#include <hip/hip_runtime.h>
#include <cmath>
#include <cstdint>

// B=64, T=64, W=20, D=1024, K=4, STRIDE=4 ; conv lengths 64->16->4->1 ; T_total=21

typedef __bf16 bf16_t;
typedef bf16_t bf16x8 __attribute__((ext_vector_type(8)));
typedef bf16_t bf16x4 __attribute__((ext_vector_type(4)));
typedef float  f32x4  __attribute__((ext_vector_type(4)));

__device__ __forceinline__ void gload_lds16(const void* g, void* l) {
    __builtin_amdgcn_global_load_lds(
        (const __attribute__((address_space(1))) void*)g,
        (__attribute__((address_space(3))) void*)l, 16, 0, 0);
}

// swizzled LDS offset (bf16 units) for logical (row, 8-elem chunk c):
// physical chunk = c ^ (row&7). Staging thread t loads logical chunk
// (t&7)^(row&7) into physical chunk (t&7), so reads use this map.
__device__ __forceinline__ int swz(int r, int c) { return (r * 8 + (c ^ (r & 7))) * 8; }

// row remap for direct stores. mode 0: identity. mode 1: conv1d stack
// (rows 0..1023 = level0 (b,16), 1024..1279 = level1 (b,4), 1280..1343 = level2)
__device__ __forceinline__ int remap_row(int gm, int mode) {
    if (mode == 0) return gm;
    if (gm < 1024) return (gm >> 4) * 21 + (gm & 15);
    if (gm < 1280) { int g = gm - 1024; return (g >> 2) * 21 + 16 + (g & 3); }
    return (gm - 1280) * 21 + 20;
}

// ---------------- merged fp32 -> bf16 cast over 4 arrays ----------------------
__global__ void cast_multi_kernel(
    const float* __restrict__ p0, bf16_t* __restrict__ q0, int n0,
    const float* __restrict__ p1, bf16_t* __restrict__ q1, int n1,
    const float* __restrict__ p2, bf16_t* __restrict__ q2, int n2,
    const float* __restrict__ p3, bf16_t* __restrict__ q3, int n3)
{
    int off = (blockIdx.x * 256 + threadIdx.x) * 4;
    const float* s; bf16_t* d;
    if (off < n0) { s = p0 + off; d = q0 + off; }
    else if ((off -= n0) < n1) { s = p1 + off; d = q1 + off; }
    else if ((off -= n1) < n2) { s = p2 + off; d = q2 + off; }
    else if ((off -= n2) < n3) { s = p3 + off; d = q3 + off; }
    else return;
    float4 v = *(const float4*)s;
    bf16x4 o = { (bf16_t)v.x, (bf16_t)v.y, (bf16_t)v.z, (bf16_t)v.w };
    *(bf16x4*)d = o;
}

// ---- weight transpose+cast: wt[o][k*1024+i] = (bf16) w[o][i*4+k] -------------
__global__ void transpose_cast_kernel(const float* __restrict__ w, bf16_t* __restrict__ wt) {
    int idx = blockIdx.x * 256 + threadIdx.x;   // 0 .. 4194304
    int i = idx & 1023;
    int k = (idx >> 10) & 3;
    int o = idx >> 12;
    wt[idx] = (bf16_t)w[(o << 12) + (i << 2) + k];
}

// ---------------- bf16 MFMA NT GEMM: C[m,n] = sum_k A[m,k]*B[n,k] -------------
// 64x64 tile, BK=64, 4 waves (each a 32x32 quadrant, 2x2 mfma_16x16x32).
// XOR-swizzled LDS (conflict-free ds_read_b128), double-buffered staging via
// global_load_lds width 16; prefetch issued between barrier and compute.
template<bool SPLIT, bool RELU, bool OUTBF16>
__global__ __launch_bounds__(256) void mgemm_kernel(
    const bf16_t* __restrict__ A, const bf16_t* __restrict__ B,
    const float* __restrict__ bias, void* __restrict__ C,
    int M, int N, int K, int Kchunk, int mode, int ldc)
{
    __shared__ __align__(16) bf16_t sA[2][4096];
    __shared__ __align__(16) bf16_t sB[2][4096];
    const int tid  = threadIdx.x;
    const int lane = tid & 63;
    const int wave = tid >> 6;
    const int m0 = blockIdx.x * 64, n0 = blockIdx.y * 64;
    int k0 = 0, kend = K;
    if (SPLIT) { k0 = blockIdx.z * Kchunk; kend = k0 + Kchunk; }

    // staging: thread t -> row sr=(t>>3) (and sr+32), physical chunk t&7,
    // logical chunk lc = (t&7) ^ (sr&7)  [(sr+32)&7 == sr&7]
    const int sr = tid >> 3;
    const int pc = tid & 7;
    const int lc = pc ^ (sr & 7);
    const bf16_t* Ag = A + (size_t)(m0 + sr) * K + lc * 8;
    const bf16_t* Bg = B + (size_t)(n0 + sr) * K + lc * 8;
    const size_t rowskip = (size_t)32 * K;

    const int wr = (wave >> 1) * 32;      // quadrant row offset
    const int wc = (wave & 1) * 32;       // quadrant col offset
    const int fm = lane & 15;             // fragment row/col within 16
    const int cb = lane >> 4;             // k-chunk base (8 elems per chunk)

    int offA[2][2], offB[2][2];           // [ks half][frag]
    #pragma unroll
    for (int h = 0; h < 2; h++) {
        offA[h][0] = swz(wr +      fm, cb + h * 4);
        offA[h][1] = swz(wr + 16 + fm, cb + h * 4);
        offB[h][0] = swz(wc +      fm, cb + h * 4);
        offB[h][1] = swz(wc + 16 + fm, cb + h * 4);
    }

    f32x4 acc[2][2];
    #pragma unroll
    for (int a = 0; a < 2; a++)
        #pragma unroll
        for (int b = 0; b < 2; b++) acc[a][b] = (f32x4){0.f, 0.f, 0.f, 0.f};

    const int nIt = (kend - k0) >> 6;
    {   // prologue: stage tile 0 into buf 0
        const bf16_t* a = Ag + k0; const bf16_t* b = Bg + k0;
        gload_lds16(a,           &sA[0][tid * 8]);
        gload_lds16(a + rowskip, &sA[0][2048 + tid * 8]);
        gload_lds16(b,           &sB[0][tid * 8]);
        gload_lds16(b + rowskip, &sB[0][2048 + tid * 8]);
    }
    for (int it = 0; it < nIt; ++it) {
        const int buf = it & 1;
        __syncthreads();                   // tile(it) staged; prev reads done
        if (it + 1 < nIt) {                // prefetch tile(it+1) into other buf
            const bf16_t* a = Ag + k0 + (it + 1) * 64;
            const bf16_t* b = Bg + k0 + (it + 1) * 64;
            bf16_t* dA = &sA[buf ^ 1][0];
            bf16_t* dB = &sB[buf ^ 1][0];
            gload_lds16(a,           dA + tid * 8);
            gload_lds16(a + rowskip, dA + 2048 + tid * 8);
            gload_lds16(b,           dB + tid * 8);
            gload_lds16(b + rowskip, dB + 2048 + tid * 8);
        }
        #pragma unroll
        for (int h = 0; h < 2; h++) {
            bf16x8 a0 = *(const bf16x8*)&sA[buf][offA[h][0]];
            bf16x8 a1 = *(const bf16x8*)&sA[buf][offA[h][1]];
            bf16x8 b0 = *(const bf16x8*)&sB[buf][offB[h][0]];
            bf16x8 b1 = *(const bf16x8*)&sB[buf][offB[h][1]];
            acc[0][0] = __builtin_amdgcn_mfma_f32_16x16x32_bf16(a0, b0, acc[0][0], 0, 0, 0);
            acc[0][1] = __builtin_amdgcn_mfma_f32_16x16x32_bf16(a0, b1, acc[0][1], 0, 0, 0);
            acc[1][0] = __builtin_amdgcn_mfma_f32_16x16x32_bf16(a1, b0, acc[1][0], 0, 0, 0);
            acc[1][1] = __builtin_amdgcn_mfma_f32_16x16x32_bf16(a1, b1, acc[1][1], 0, 0, 0);
        }
    }

    // C/D layout: col = lane&15, row = (lane>>4)*4 + reg   [verified m89/m91]
    if (SPLIT) {
        float* Cz = (float*)C + (size_t)blockIdx.z * M * N;
        #pragma unroll
        for (int im = 0; im < 2; im++)
            #pragma unroll
            for (int rr = 0; rr < 4; rr++) {
                int gm = m0 + wr + im * 16 + (lane >> 4) * 4 + rr;
                #pragma unroll
                for (int in_ = 0; in_ < 2; in_++) {
                    int cg = n0 + wc + in_ * 16 + (lane & 15);
                    Cz[(size_t)gm * N + cg] = acc[im][in_][rr];
                }
            }
    } else {
        #pragma unroll
        for (int im = 0; im < 2; im++)
            #pragma unroll
            for (int rr = 0; rr < 4; rr++) {
                int gm = m0 + wr + im * 16 + (lane >> 4) * 4 + rr;
                int row = remap_row(gm, mode);
                #pragma unroll
                for (int in_ = 0; in_ < 2; in_++) {
                    int cg = n0 + wc + in_ * 16 + (lane & 15);
                    float v = acc[im][in_][rr];
                    if (bias) v += bias[cg];
                    if (RELU) v = fmaxf(v, 0.f);
                    if (OUTBF16) ((bf16_t*)C)[(size_t)row * ldc + cg] = (bf16_t)v;
                    else         ((float*)C)[(size_t)row * ldc + cg] = v;
                }
            }
    }
}

// ------- split-K reduce + bias + relu -> bf16 and/or fp32 (identity remap) ----
__global__ void epilogueB_kernel(const float* __restrict__ CP_, int nz,
    const float* __restrict__ bias, bf16_t* __restrict__ D, float* __restrict__ D2,
    int MN, int N, int relu)
{
    int idx = blockIdx.x * 256 + threadIdx.x;
    if (idx >= MN) return;
    int n = idx % N;
    float s = 0.f;
    for (int z = 0; z < nz; z++) s += CP_[(size_t)z * MN + idx];
    if (bias) s += bias[n];
    if (relu) s = fmaxf(s, 0.f);
    if (D)  D[idx] = (bf16_t)s;
    if (D2) D2[idx] = s;
}

// ---------------- per-row L2 norm of bf16 rows (value only) -------------------
__global__ void rownorm_kernel(const bf16_t* __restrict__ X, float* __restrict__ nrm, int D) {
    int r = blockIdx.x;
    const bf16_t* x = X + (size_t)r * D;
    float s = 0.f;
    for (int d = threadIdx.x; d < D; d += blockDim.x) { float v = (float)x[d]; s += v * v; }
    #pragma unroll
    for (int o = 32; o; o >>= 1) s += __shfl_xor(s, o, 64);
    __shared__ float red[4];
    if ((threadIdx.x & 63) == 0) red[threadIdx.x >> 6] = s;
    __syncthreads();
    if (threadIdx.x == 0) nrm[r] = sqrtf(red[0] + red[1] + red[2] + red[3]);
}

// ---------------- two-source per-row L2 normalize (fp32) ----------------------
__global__ void l2normalize2_kernel(const float* __restrict__ X0, float* __restrict__ Y0,
                                    const float* __restrict__ X1, float* __restrict__ Y1,
                                    int D) {
    int r = blockIdx.x & 63;
    const float* x = (blockIdx.x < 64 ? X0 : X1) + (size_t)r * D;
    float*       y = (blockIdx.x < 64 ? Y0 : Y1) + (size_t)r * D;
    float s = 0.f;
    for (int d = threadIdx.x; d < D; d += blockDim.x) { float v = x[d]; s += v * v; }
    #pragma unroll
    for (int o = 32; o; o >>= 1) s += __shfl_xor(s, o, 64);
    __shared__ float red[4];
    __shared__ float tot;
    if ((threadIdx.x & 63) == 0) red[threadIdx.x >> 6] = s;
    __syncthreads();
    if (threadIdx.x == 0) tot = 1.0f / fmaxf(sqrtf(red[0] + red[1] + red[2] + red[3]), 1e-8f);
    __syncthreads();
    float inv = tot;
    for (int d = threadIdx.x; d < D; d += blockDim.x) y[d] = x[d] * inv;
}

// ---------------- Gram: G[i][w][w'] = dot(words[i,w], words[i,w']) ------------
__global__ void gram_kernel(const float* __restrict__ words, float* __restrict__ G) {
    int i = blockIdx.x;                       // 64
    int wave = threadIdx.x >> 6;
    int lane = threadIdx.x & 63;
    int pair = blockIdx.y * 4 + wave;         // 0..399
    int w = pair / 20, w2 = pair % 20;
    const float* a = words + ((size_t)i * 20 + w) * 1024;
    const float* b = words + ((size_t)i * 20 + w2) * 1024;
    float s = 0.f;
    #pragma unroll
    for (int q = 0; q < 16; q++) { int d = lane + 64 * q; s += a[d] * b[d]; }
    #pragma unroll
    for (int o = 32; o; o >>= 1) s += __shfl_xor(s, o, 64);
    if (lane == 0) G[(size_t)i * 400 + pair] = s;
}

// ---------------- sim via logits + Gram quadratic form ------------------------
__global__ void sim_kernel(const float* __restrict__ S_, const float* __restrict__ G_,
                           const float* __restrict__ VN_, const int* __restrict__ wmask,
                           float* __restrict__ SA_) {
    int item = blockIdx.x * 4 + (threadIdx.x >> 6);   // 0 .. 86016
    int lane = threadIdx.x & 63;
    int t = item % 21;
    int ij = item / 21;
    int j = ij & 63, i = ij >> 6;

    float s_raw = 0.f; bool act = false;
    if (lane < 20) {
        s_raw = S_[(size_t)(j * 21 + t) * 1280 + i * 20 + lane];
        act = (wmask[i * 20 + lane] != 0);
    }
    float s_m = act ? s_raw : -1e30f;
    float mx = s_m;
    #pragma unroll
    for (int o = 16; o; o >>= 1) mx = fmaxf(mx, __shfl_xor(mx, o, 32));
    float p = act ? __expf(s_m - mx) : 0.f;
    float denom = p, num = p * s_raw;
    #pragma unroll
    for (int o = 16; o; o >>= 1) { denom += __shfl_xor(denom, o, 32); num += __shfl_xor(num, o, 32); }

    const float* Gi = G_ + (size_t)i * 400;
    float c = 0.f;
    #pragma unroll
    for (int w = 0; w < 20; w++) {
        float pw = __shfl(p, w, 32);
        float gv = (lane < 20) ? Gi[w * 20 + lane] : 0.f;
        c += pw * gv;
    }
    float pc = p * c;
    #pragma unroll
    for (int o = 16; o; o >>= 1) pc += __shfl_xor(pc, o, 32);

    if (lane == 0) {
        float dot = num / denom;
        float vsn = sqrtf(fmaxf(pc, 0.f)) / denom;
        float nv = VN_[j * 21 + t];
        float sim = dot / (fmaxf(nv, 1e-8f) * fmaxf(vsn, 1e-8f));
        SA_[item] = sim;
    }
}

// ---------------- scores mean + positive_map ----------------------------------
__global__ void scores_kernel(const float* __restrict__ SA_, float* __restrict__ SC_,
                              float* __restrict__ out) {
    int idx = blockIdx.x * 256 + threadIdx.x;  // 4096 = i*64+j
    int i = idx >> 6, j = idx & 63;
    const float* row = SA_ + (size_t)idx * 21;
    float s = 0.f;
    #pragma unroll
    for (int t = 0; t < 21; t++) s += row[t];
    SC_[idx] = s * (1.0f / 21.0f);
    if (i == j) {
        #pragma unroll
        for (int t = 0; t < 21; t++) out[1 + i * 21 + t] = row[t];
    }
}

// ---------------- global-branch scores ----------------------------------------
__global__ void gscore_kernel(const float* __restrict__ SN_, const float* __restrict__ GN_,
                              float* __restrict__ GS_) {
    int item = blockIdx.x * 4 + (threadIdx.x >> 6);  // 4096
    int i = item >> 6, j = item & 63;
    int lane = threadIdx.x & 63;
    const float* a = SN_ + (size_t)i * 1024;
    const float* b = GN_ + (size_t)j * 1024;
    float s = 0.f;
    #pragma unroll
    for (int q = 0; q < 16; q++) { int d = lane + 64 * q; s += a[d] * b[d]; }
    #pragma unroll
    for (int o = 32; o; o >>= 1) s += __shfl_xor(s, o, 64);
    if (lane == 0) GS_[item] = s;
}

// ---------------- margin ranking loss -----------------------------------------
__global__ void loss_kernel(const float* __restrict__ SC_, const float* __restrict__ GS_,
                            float* __restrict__ out) {
    __shared__ float d1[64], d2[64], red[4];
    int tid = threadIdx.x;
    if (tid < 64) { d1[tid] = SC_[tid * 65]; d2[tid] = GS_[tid * 65]; }
    __syncthreads();
    float acc = 0.f;
    for (int idx = tid; idx < 4096; idx += 256) {
        int i = idx >> 6, j = idx & 63;
        if (i != j) {
            float s = SC_[idx];
            acc += fmaxf(0.2f + s - d1[i], 0.f) + fmaxf(0.2f + s - d1[j], 0.f);
            float g = GS_[idx];
            acc += fmaxf(0.2f + g - d2[i], 0.f) + fmaxf(0.2f + g - d2[j], 0.f);
        }
    }
    #pragma unroll
    for (int o = 32; o; o >>= 1) acc += __shfl_xor(acc, o, 64);
    if ((tid & 63) == 0) red[tid >> 6] = acc;
    __syncthreads();
    if (tid == 0) out[0] = (red[0] + red[1] + red[2] + red[3]) * (1.0f / 64.0f);
}

// ------------------------------------------------------------------------------
extern "C" void kernel_launch(void* const* d_in, const int* in_sizes, int n_in,
                              void* d_out, int out_size, void* d_ws, size_t ws_size,
                              hipStream_t stream)
{
    const float* video     = (const float*)d_in[0];
    const float* words     = (const float*)d_in[1];
    const int*   w_masks   = (const int*)  d_in[2];
    const float* sentences = (const float*)d_in[3];
    const float* conv0_w   = (const float*)d_in[4];
    const float* conv0_b   = (const float*)d_in[5];
    const float* conv1_w   = (const float*)d_in[6];
    const float* conv1_b   = (const float*)d_in[7];
    const float* conv2_w   = (const float*)d_in[8];
    const float* conv2_b   = (const float*)d_in[9];
    const float* conv1d_w  = (const float*)d_in[10];
    const float* conv1d_b  = (const float*)d_in[11];
    const float* fc_w      = (const float*)d_in[12];
    const float* fc_b      = (const float*)d_in[13];
    float* out = (float*)d_out;
    float* ws = (float*)d_ws;

    // workspace (float units), total 7,592,256 f = 30.4 MB.
    // Aliases: WTb (dead after conv2 GEMM) <-> Sb (written by attn GEMM later);
    //          Vb  (dead after conv0 GEMM) <-> CP (first written by conv1 GEMM).
    bf16_t* WTb    = (bf16_t*)(ws + 0);            // 4,194,304 bf16
    float*  Sb     = ws + 0;                       // 1,720,320 f (alias of WTb)
    bf16_t* Vb     = (bf16_t*)(ws + 2097152);      // 4,194,304 bf16
    float*  CP     = ws + 2097152;                 // up to 1,048,576 f (alias of Vb)
    bf16_t* Astack = (bf16_t*)(ws + 4194304);      // 1344x1024 bf16 [A1|A2|A3]
    bf16_t* VCb    = (bf16_t*)(ws + 4882432);      // 1344x1024 bf16
    bf16_t* Wordsb = (bf16_t*)(ws + 5570560);      // 1,310,720 bf16
    bf16_t* C1b    = (bf16_t*)(ws + 6225920);      // 1,048,576 bf16
    bf16_t* Fb     = (bf16_t*)(ws + 6750208);      // 1,048,576 bf16
    float*  VN     = ws + 7274496;                 // 1,344
    float*  GR     = ws + 7275840;                 // 25,600
    float*  SA     = ws + 7301440;                 // 86,016
    float*  SC     = ws + 7387456;                 // 4,096
    float*  GV     = ws + 7391552;                 // 65,536
    float*  GN     = ws + 7457088;                 // 65,536
    float*  SN     = ws + 7522624;                 // 65,536
    float*  GS     = ws + 7588160;                 // 4,096

    bf16_t* A2b = Astack + 1048576;   // rows 1024..1279
    bf16_t* A3b = Astack + 1310720;   // rows 1280..1343

    dim3 blk(256);

    // one merged cast: video, words, conv1d_w, fc_w  (7,602,176 elems / 4 / 256)
    cast_multi_kernel<<<7424, blk, 0, stream>>>(
        video, Vb, 4194304, words, Wordsb, 1310720,
        conv1d_w, C1b, 1048576, fc_w, Fb, 1048576);

    // conv0: (1024,4096)x(1024,4096)^T +bias +relu -> Astack rows 0..1023
    transpose_cast_kernel<<<16384, blk, 0, stream>>>(conv0_w, WTb);
    mgemm_kernel<false,true,true><<<dim3(16,16,1), blk, 0, stream>>>(
        Vb, WTb, conv0_b, Astack, 1024, 1024, 4096, 0, 0, 1024);

    // conv1: M=256 (A1 viewed as 256x4096), split-K x4
    transpose_cast_kernel<<<16384, blk, 0, stream>>>(conv1_w, WTb);
    mgemm_kernel<true,false,false><<<dim3(4,16,4), blk, 0, stream>>>(
        Astack, WTb, nullptr, CP, 256, 1024, 4096, 1024, 0, 0);
    epilogueB_kernel<<<1024, blk, 0, stream>>>(CP, 4, conv1_b, A2b, nullptr, 262144, 1024, 1);

    // conv2: M=64 (A2 viewed as 64x4096), split-K x16
    transpose_cast_kernel<<<16384, blk, 0, stream>>>(conv2_w, WTb);
    mgemm_kernel<true,false,false><<<dim3(1,16,16), blk, 0, stream>>>(
        A2b, WTb, nullptr, CP, 64, 1024, 4096, 256, 0, 0);
    epilogueB_kernel<<<256, blk, 0, stream>>>(CP, 16, conv2_b, A3b, nullptr, 65536, 1024, 1);

    // conv1d (all 3 levels in one GEMM): M=1344, remap mode 1 -> VCb rows j*21+t
    mgemm_kernel<false,false,true><<<dim3(21,16,1), blk, 0, stream>>>(
        Astack, C1b, conv1d_b, VCb, 1344, 1024, 1024, 0, 1, 1024);

    // fc: g = A3 @ fc_w^T + fc_b  (bf16 MFMA, split-K x8) -> GV fp32
    mgemm_kernel<true,false,false><<<dim3(1,16,8), blk, 0, stream>>>(
        A3b, Fb, nullptr, CP, 64, 1024, 1024, 128, 0, 0);
    epilogueB_kernel<<<256, blk, 0, stream>>>(CP, 8, fc_b, nullptr, GV, 65536, 1024, 0);

    // attention logits: Sb[(j,t),(i,w)] = VCb . Wordsb^T  (1344x1280x1024) fp32
    mgemm_kernel<false,false,false><<<dim3(21,20,1), blk, 0, stream>>>(
        VCb, Wordsb, nullptr, Sb, 1344, 1280, 1024, 0, 0, 1280);

    rownorm_kernel<<<1344, blk, 0, stream>>>(VCb, VN, 1024);
    gram_kernel<<<dim3(64,100), blk, 0, stream>>>(words, GR);
    sim_kernel<<<21504, blk, 0, stream>>>(Sb, GR, VN, w_masks, SA);
    scores_kernel<<<16, blk, 0, stream>>>(SA, SC, out);

    l2normalize2_kernel<<<128, blk, 0, stream>>>(GV, GN, sentences, SN, 1024);
    gscore_kernel<<<1024, blk, 0, stream>>>(SN, GN, GS);
    loss_kernel<<<1, blk, 0, stream>>>(SC, GS, out);
}

// Round 4
// 299.805 us; speedup vs baseline: 2.4659x; 1.0789x over previous
//
#include <hip/hip_runtime.h>
#include <cmath>
#include <cstdint>

// B=64, T=64, W=20, D=1024, K=4, STRIDE=4 ; conv lengths 64->16->4->1 ; T_total=21

typedef __bf16 bf16_t;
typedef bf16_t bf16x8 __attribute__((ext_vector_type(8)));
typedef bf16_t bf16x4 __attribute__((ext_vector_type(4)));
typedef float  f32x4  __attribute__((ext_vector_type(4)));

__device__ __forceinline__ void gload_lds16(const void* g, void* l) {
    __builtin_amdgcn_global_load_lds(
        (const __attribute__((address_space(1))) void*)g,
        (__attribute__((address_space(3))) void*)l, 16, 0, 0);
}

// swizzled LDS offset (bf16 units) for logical (row, 8-elem chunk c):
// physical chunk = c ^ (row&7); staging thread t loads logical chunk
// (t&7)^(row&7) into physical chunk (t&7).  [R3: conflicts 6.29M -> 0]
__device__ __forceinline__ int swz(int r, int c) { return (r * 8 + (c ^ (r & 7))) * 8; }

// conv1d stack row remap: rows 0..1023 = level0 (b,16), 1024..1279 = level1 (b,4),
// 1280..1343 = level2 (b,1)  ->  VC row j*21 + t
__device__ __forceinline__ int remap1(int gm) {
    if (gm < 1024) return (gm >> 4) * 21 + (gm & 15);
    if (gm < 1280) { int g = gm - 1024; return (g >> 2) * 21 + 16 + (g & 3); }
    return (gm - 1280) * 21 + 20;
}

// ---------------- merged fp32 -> bf16 cast over up to 2 arrays ----------------
__global__ void cast_multi_kernel(
    const float* __restrict__ p0, bf16_t* __restrict__ q0, int n0,
    const float* __restrict__ p1, bf16_t* __restrict__ q1, int n1)
{
    int off = (blockIdx.x * 256 + threadIdx.x) * 4;
    const float* s; bf16_t* d;
    if (off < n0) { s = p0 + off; d = q0 + off; }
    else if ((off -= n0) < n1) { s = p1 + off; d = q1 + off; }
    else return;
    float4 v = *(const float4*)s;
    bf16x4 o = { (bf16_t)v.x, (bf16_t)v.y, (bf16_t)v.z, (bf16_t)v.w };
    *(bf16x4*)d = o;
}

// ---- weight transpose+cast: wt[o][k*1024+i] = (bf16) w[o][i*4+k] -------------
__global__ void transpose_cast_kernel(const float* __restrict__ w, bf16_t* __restrict__ wt) {
    int idx = blockIdx.x * 256 + threadIdx.x;   // 0 .. 4194304
    int i = idx & 1023;
    int k = (idx >> 10) & 3;
    int o = idx >> 12;
    wt[idx] = (bf16_t)w[(o << 12) + (i << 2) + k];
}

// ---------------- bf16 MFMA NT split-K GEMM -> fp32 partials ------------------
// 64x64 tile, BK=64, 4 waves (each 32x32 quadrant, 2x2 mfma_16x16x32), XOR-
// swizzled LDS, double-buffered global_load_lds staging. Always split-K:
// slice z covers K range [z*Kchunk, (z+1)*Kchunk) -> CP + z*cpSlice.
// fcTile: blockIdx.x at which A switches to row aRow0 and B switches to B2
// (used to fold the fc GEMM into the conv1d launch); pass -1 otherwise.
__global__ __launch_bounds__(256) void mgemm_kernel(
    const bf16_t* __restrict__ A, const bf16_t* __restrict__ B,
    const bf16_t* __restrict__ B2, float* __restrict__ CP,
    int N, int K, int Kchunk, int fcTile, int aRow0, int cpSlice)
{
    __shared__ __align__(16) bf16_t sA[2][4096];
    __shared__ __align__(16) bf16_t sB[2][4096];
    const int tid  = threadIdx.x;
    const int lane = tid & 63;
    const int wave = tid >> 6;
    const int bx = blockIdx.x;
    const int m0C = bx * 64;
    int m0A = m0C;
    const bf16_t* Buse = B;
    if (bx == fcTile) { m0A = aRow0; Buse = B2; }
    const int n0 = blockIdx.y * 64;
    const int k0 = blockIdx.z * Kchunk;

    const int sr = tid >> 3;              // staging row 0..31
    const int pc = tid & 7;               // physical chunk
    const int lc = pc ^ (sr & 7);         // logical chunk
    const bf16_t* Ag = A + (size_t)(m0A + sr) * K + lc * 8;
    const bf16_t* Bg = Buse + (size_t)(n0 + sr) * K + lc * 8;
    const size_t rowskip = (size_t)32 * K;

    const int wr = (wave >> 1) * 32;
    const int wc = (wave & 1) * 32;
    const int fm = lane & 15;
    const int cb = lane >> 4;

    int offA[2][2], offB[2][2];
    #pragma unroll
    for (int h = 0; h < 2; h++) {
        offA[h][0] = swz(wr +      fm, cb + h * 4);
        offA[h][1] = swz(wr + 16 + fm, cb + h * 4);
        offB[h][0] = swz(wc +      fm, cb + h * 4);
        offB[h][1] = swz(wc + 16 + fm, cb + h * 4);
    }

    f32x4 acc[2][2];
    #pragma unroll
    for (int a = 0; a < 2; a++)
        #pragma unroll
        for (int b = 0; b < 2; b++) acc[a][b] = (f32x4){0.f, 0.f, 0.f, 0.f};

    const int nIt = Kchunk >> 6;
    {   // prologue: stage tile 0 into buf 0
        const bf16_t* a = Ag + k0; const bf16_t* b = Bg + k0;
        gload_lds16(a,           &sA[0][tid * 8]);
        gload_lds16(a + rowskip, &sA[0][2048 + tid * 8]);
        gload_lds16(b,           &sB[0][tid * 8]);
        gload_lds16(b + rowskip, &sB[0][2048 + tid * 8]);
    }
    for (int it = 0; it < nIt; ++it) {
        const int buf = it & 1;
        __syncthreads();
        if (it + 1 < nIt) {
            const bf16_t* a = Ag + k0 + (it + 1) * 64;
            const bf16_t* b = Bg + k0 + (it + 1) * 64;
            bf16_t* dA = &sA[buf ^ 1][0];
            bf16_t* dB = &sB[buf ^ 1][0];
            gload_lds16(a,           dA + tid * 8);
            gload_lds16(a + rowskip, dA + 2048 + tid * 8);
            gload_lds16(b,           dB + tid * 8);
            gload_lds16(b + rowskip, dB + 2048 + tid * 8);
        }
        #pragma unroll
        for (int h = 0; h < 2; h++) {
            bf16x8 a0 = *(const bf16x8*)&sA[buf][offA[h][0]];
            bf16x8 a1 = *(const bf16x8*)&sA[buf][offA[h][1]];
            bf16x8 b0 = *(const bf16x8*)&sB[buf][offB[h][0]];
            bf16x8 b1 = *(const bf16x8*)&sB[buf][offB[h][1]];
            acc[0][0] = __builtin_amdgcn_mfma_f32_16x16x32_bf16(a0, b0, acc[0][0], 0, 0, 0);
            acc[0][1] = __builtin_amdgcn_mfma_f32_16x16x32_bf16(a0, b1, acc[0][1], 0, 0, 0);
            acc[1][0] = __builtin_amdgcn_mfma_f32_16x16x32_bf16(a1, b0, acc[1][0], 0, 0, 0);
            acc[1][1] = __builtin_amdgcn_mfma_f32_16x16x32_bf16(a1, b1, acc[1][1], 0, 0, 0);
        }
    }

    // C/D layout: col = lane&15, row = (lane>>4)*4 + reg   [verified m89/m91]
    float* Cz = CP + (size_t)blockIdx.z * cpSlice;
    #pragma unroll
    for (int im = 0; im < 2; im++)
        #pragma unroll
        for (int rr = 0; rr < 4; rr++) {
            int gm = m0C + wr + im * 16 + (lane >> 4) * 4 + rr;
            #pragma unroll
            for (int in_ = 0; in_ < 2; in_++) {
                int cg = n0 + wc + in_ * 16 + (lane & 15);
                Cz[(size_t)gm * N + cg] = acc[im][in_][rr];
            }
        }
}

// ------- split-K reduce + bias + relu -> bf16 and/or fp32 (identity remap) ----
__global__ void epilogueB_kernel(const float* __restrict__ CP_, int nz,
    const float* __restrict__ bias, bf16_t* __restrict__ D, float* __restrict__ D2,
    int MN, int N, int relu)
{
    int idx = blockIdx.x * 256 + threadIdx.x;
    if (idx >= MN) return;
    int n = idx % N;
    float s = 0.f;
    for (int z = 0; z < nz; z++) s += CP_[(size_t)z * MN + idx];
    if (bias) s += bias[n];
    if (relu) s = fmaxf(s, 0.f);
    if (D)  D[idx] = (bf16_t)s;
    if (D2) D2[idx] = s;
}

// ------- conv1d+fc combined epilogue: rows<1344 -> VCb (bf16, remap1),
//         rows>=1344 -> GV (fp32). 2 split-K slices. --------------------------
__global__ void epilogueCF_kernel(const float* __restrict__ CP_,
    const float* __restrict__ bias1, const float* __restrict__ biasf,
    bf16_t* __restrict__ VCb, float* __restrict__ GV)
{
    int idx = blockIdx.x * 256 + threadIdx.x;       // < 1441792
    int row = idx >> 10, n = idx & 1023;
    float s = CP_[idx] + CP_[idx + 1441792];
    if (row < 1344) VCb[(size_t)remap1(row) * 1024 + n] = (bf16_t)(s + bias1[n]);
    else            GV[(size_t)(row - 1344) * 1024 + n] = s + biasf[n];
}

// ---------------- per-row L2 norm of bf16 rows (value only) -------------------
__global__ void rownorm_kernel(const bf16_t* __restrict__ X, float* __restrict__ nrm, int D) {
    int r = blockIdx.x;
    const bf16_t* x = X + (size_t)r * D;
    float s = 0.f;
    for (int d = threadIdx.x; d < D; d += blockDim.x) { float v = (float)x[d]; s += v * v; }
    #pragma unroll
    for (int o = 32; o; o >>= 1) s += __shfl_xor(s, o, 64);
    __shared__ float red[4];
    if ((threadIdx.x & 63) == 0) red[threadIdx.x >> 6] = s;
    __syncthreads();
    if (threadIdx.x == 0) nrm[r] = sqrtf(red[0] + red[1] + red[2] + red[3]);
}

// ---------------- two-source per-row L2 normalize (fp32) ----------------------
__global__ void l2normalize2_kernel(const float* __restrict__ X0, float* __restrict__ Y0,
                                    const float* __restrict__ X1, float* __restrict__ Y1,
                                    int D) {
    int r = blockIdx.x & 63;
    const float* x = (blockIdx.x < 64 ? X0 : X1) + (size_t)r * D;
    float*       y = (blockIdx.x < 64 ? Y0 : Y1) + (size_t)r * D;
    float s = 0.f;
    for (int d = threadIdx.x; d < D; d += blockDim.x) { float v = x[d]; s += v * v; }
    #pragma unroll
    for (int o = 32; o; o >>= 1) s += __shfl_xor(s, o, 64);
    __shared__ float red[4];
    __shared__ float tot;
    if ((threadIdx.x & 63) == 0) red[threadIdx.x >> 6] = s;
    __syncthreads();
    if (threadIdx.x == 0) tot = 1.0f / fmaxf(sqrtf(red[0] + red[1] + red[2] + red[3]), 1e-8f);
    __syncthreads();
    float inv = tot;
    for (int d = threadIdx.x; d < D; d += blockDim.x) y[d] = x[d] * inv;
}

// ------- Gram from bf16 words: G[i][w][w'] = dot(Wb[i,w], Wb[i,w']) -----------
__global__ void gram_kernel(const bf16_t* __restrict__ Wb, float* __restrict__ G) {
    int i = blockIdx.x;                       // 64
    int wave = threadIdx.x >> 6;
    int lane = threadIdx.x & 63;
    int pair = blockIdx.y * 4 + wave;         // 0..399
    int w = pair / 20, w2 = pair % 20;
    const bf16_t* a = Wb + (((size_t)i * 20 + w)  << 10) + lane * 16;
    const bf16_t* b = Wb + (((size_t)i * 20 + w2) << 10) + lane * 16;
    bf16x8 a0 = *(const bf16x8*)a, a1 = *(const bf16x8*)(a + 8);
    bf16x8 b0 = *(const bf16x8*)b, b1 = *(const bf16x8*)(b + 8);
    float s = 0.f;
    #pragma unroll
    for (int e = 0; e < 8; e++)
        s += (float)a0[e] * (float)b0[e] + (float)a1[e] * (float)b1[e];
    #pragma unroll
    for (int o = 32; o; o >>= 1) s += __shfl_xor(s, o, 64);
    if (lane == 0) G[(size_t)i * 400 + pair] = s;
}

// ---------------- sim via logits + Gram quadratic form ------------------------
__global__ void sim_kernel(const float* __restrict__ S_, const float* __restrict__ G_,
                           const float* __restrict__ VN_, const int* __restrict__ wmask,
                           float* __restrict__ SA_) {
    int item = blockIdx.x * 4 + (threadIdx.x >> 6);   // 0 .. 86016
    int lane = threadIdx.x & 63;
    int t = item % 21;
    int ij = item / 21;
    int j = ij & 63, i = ij >> 6;

    float s_raw = 0.f; bool act = false;
    if (lane < 20) {
        s_raw = S_[(size_t)(j * 21 + t) * 1280 + i * 20 + lane];
        act = (wmask[i * 20 + lane] != 0);
    }
    float s_m = act ? s_raw : -1e30f;
    float mx = s_m;
    #pragma unroll
    for (int o = 16; o; o >>= 1) mx = fmaxf(mx, __shfl_xor(mx, o, 32));
    float p = act ? __expf(s_m - mx) : 0.f;
    float denom = p, num = p * s_raw;
    #pragma unroll
    for (int o = 16; o; o >>= 1) { denom += __shfl_xor(denom, o, 32); num += __shfl_xor(num, o, 32); }

    const float* Gi = G_ + (size_t)i * 400;
    float c = 0.f;
    #pragma unroll
    for (int w = 0; w < 20; w++) {
        float pw = __shfl(p, w, 32);
        float gv = (lane < 20) ? Gi[w * 20 + lane] : 0.f;
        c += pw * gv;
    }
    float pc = p * c;
    #pragma unroll
    for (int o = 16; o; o >>= 1) pc += __shfl_xor(pc, o, 32);

    if (lane == 0) {
        float dot = num / denom;
        float vsn = sqrtf(fmaxf(pc, 0.f)) / denom;
        float nv = VN_[j * 21 + t];
        float sim = dot / (fmaxf(nv, 1e-8f) * fmaxf(vsn, 1e-8f));
        SA_[item] = sim;
    }
}

// ---------------- scores mean + positive_map ----------------------------------
__global__ void scores_kernel(const float* __restrict__ SA_, float* __restrict__ SC_,
                              float* __restrict__ out) {
    int idx = blockIdx.x * 256 + threadIdx.x;  // 4096 = i*64+j
    int i = idx >> 6, j = idx & 63;
    const float* row = SA_ + (size_t)idx * 21;
    float s = 0.f;
    #pragma unroll
    for (int t = 0; t < 21; t++) s += row[t];
    SC_[idx] = s * (1.0f / 21.0f);
    if (i == j) {
        #pragma unroll
        for (int t = 0; t < 21; t++) out[1 + i * 21 + t] = row[t];
    }
}

// ---------------- global-branch scores ----------------------------------------
__global__ void gscore_kernel(const float* __restrict__ SN_, const float* __restrict__ GN_,
                              float* __restrict__ GS_) {
    int item = blockIdx.x * 4 + (threadIdx.x >> 6);  // 4096
    int i = item >> 6, j = item & 63;
    int lane = threadIdx.x & 63;
    const float* a = SN_ + (size_t)i * 1024;
    const float* b = GN_ + (size_t)j * 1024;
    float s = 0.f;
    #pragma unroll
    for (int q = 0; q < 16; q++) { int d = lane + 64 * q; s += a[d] * b[d]; }
    #pragma unroll
    for (int o = 32; o; o >>= 1) s += __shfl_xor(s, o, 64);
    if (lane == 0) GS_[item] = s;
}

// ---------------- margin ranking loss -----------------------------------------
__global__ void loss_kernel(const float* __restrict__ SC_, const float* __restrict__ GS_,
                            float* __restrict__ out) {
    __shared__ float d1[64], d2[64], red[4];
    int tid = threadIdx.x;
    if (tid < 64) { d1[tid] = SC_[tid * 65]; d2[tid] = GS_[tid * 65]; }
    __syncthreads();
    float acc = 0.f;
    for (int idx = tid; idx < 4096; idx += 256) {
        int i = idx >> 6, j = idx & 63;
        if (i != j) {
            float s = SC_[idx];
            acc += fmaxf(0.2f + s - d1[i], 0.f) + fmaxf(0.2f + s - d1[j], 0.f);
            float g = GS_[idx];
            acc += fmaxf(0.2f + g - d2[i], 0.f) + fmaxf(0.2f + g - d2[j], 0.f);
        }
    }
    #pragma unroll
    for (int o = 32; o; o >>= 1) acc += __shfl_xor(acc, o, 64);
    if ((tid & 63) == 0) red[tid >> 6] = acc;
    __syncthreads();
    if (tid == 0) out[0] = (red[0] + red[1] + red[2] + red[3]) * (1.0f / 64.0f);
}

// ------------------------------------------------------------------------------
extern "C" void kernel_launch(void* const* d_in, const int* in_sizes, int n_in,
                              void* d_out, int out_size, void* d_ws, size_t ws_size,
                              hipStream_t stream)
{
    const float* video     = (const float*)d_in[0];
    const float* words     = (const float*)d_in[1];
    const int*   w_masks   = (const int*)  d_in[2];
    const float* sentences = (const float*)d_in[3];
    const float* conv0_w   = (const float*)d_in[4];
    const float* conv0_b   = (const float*)d_in[5];
    const float* conv1_w   = (const float*)d_in[6];
    const float* conv1_b   = (const float*)d_in[7];
    const float* conv2_w   = (const float*)d_in[8];
    const float* conv2_b   = (const float*)d_in[9];
    const float* conv1d_w  = (const float*)d_in[10];
    const float* conv1d_b  = (const float*)d_in[11];
    const float* fc_w      = (const float*)d_in[12];
    const float* fc_b      = (const float*)d_in[13];
    float* out = (float*)d_out;
    float* ws = (float*)d_ws;

    // ---- workspace (float units), total 8,323,072 f = 33.3 MB ----------------
    // [0, 2M): WTb (transposed conv weights, reused 3x; dead after conv2 GEMM)
    //          -> then Sb (1,720,320 f attn logits) + smalls in the tail.
    // [2M, 6M) pool:
    //   phase A (conv0):  Vb bf16 video @2M..4M ; CP0 (2 x 1M f) @4M..6M
    //   phase B (after):  C1b @2M ; Fb @2.5M ; CP1/CP2 @4M.. ; CPcf @3M..5.88M
    //   phase C (attn):   CPat (2 x 1,720,320 f) @2M..5.28M
    // [6M, ..): Astack, VCb, Wordsb
    bf16_t* WTb    = (bf16_t*)(ws + 0);
    float*  Sb     = ws + 0;                       // 1,720,320 f
    float*  VN     = ws + 1720320;                 // 1,344
    float*  GR     = ws + 1721664;                 // 25,600
    float*  SA     = ws + 1747264;                 // 86,016
    float*  SC     = ws + 1833280;                 // 4,096
    float*  GV     = ws + 1837376;                 // 65,536
    float*  GN     = ws + 1902912;                 // 65,536
    float*  SN     = ws + 1968448;                 // 65,536
    float*  GS     = ws + 2033984;                 // 4,096 (ends 2,038,080 < 2M)
    bf16_t* Vb     = (bf16_t*)(ws + 2097152);      // 4,194,304 bf16
    float*  CP0    = ws + 4194304;                 // 2 x 1,048,576 f
    bf16_t* C1b    = (bf16_t*)(ws + 2097152);      // 1,048,576 bf16 (after conv0)
    bf16_t* Fb     = (bf16_t*)(ws + 2621440);      // 1,048,576 bf16
    float*  CP1    = ws + 4194304;                 // 8 x 262,144 f
    float*  CP2    = ws + 4194304;                 // 16 x 65,536 f
    float*  CPcf   = ws + 3145728;                 // 2 x 1,441,792 f (ends 6,029,312)
    float*  CPat   = ws + 2097152;                 // 2 x 1,720,320 f (ends 5,537,792)
    bf16_t* Astack = (bf16_t*)(ws + 6291456);      // 1344x1024 bf16
    bf16_t* VCb    = (bf16_t*)(ws + 6979584);      // 1344x1024 bf16
    bf16_t* Wordsb = (bf16_t*)(ws + 7667712);      // 1,310,720 bf16 (ends 8,323,072)

    bf16_t* A2b = Astack + 1048576;   // rows 1024..1279
    bf16_t* A3b = Astack + 1310720;   // rows 1280..1343

    dim3 blk(256);

    // 1. cast video + words to bf16
    cast_multi_kernel<<<5376, blk, 0, stream>>>(video, Vb, 4194304, words, Wordsb, 1310720);

    // 2-4. conv0: M=1024 N=1024 K=4096, split-K x2 -> 512 blocks
    transpose_cast_kernel<<<16384, blk, 0, stream>>>(conv0_w, WTb);
    mgemm_kernel<<<dim3(16,16,2), blk, 0, stream>>>(
        Vb, WTb, nullptr, CP0, 1024, 4096, 2048, -1, 0, 1048576);
    epilogueB_kernel<<<4096, blk, 0, stream>>>(CP0, 2, conv0_b, Astack, nullptr, 1048576, 1024, 1);

    // 5. cast conv1d_w + fc_w (into pool space freed by Vb)
    cast_multi_kernel<<<2048, blk, 0, stream>>>(conv1d_w, C1b, 1048576, fc_w, Fb, 1048576);

    // 6-8. conv1: M=256 K=4096, split-K x8 -> 512 blocks
    transpose_cast_kernel<<<16384, blk, 0, stream>>>(conv1_w, WTb);
    mgemm_kernel<<<dim3(4,16,8), blk, 0, stream>>>(
        Astack, WTb, nullptr, CP1, 1024, 4096, 512, -1, 0, 262144);
    epilogueB_kernel<<<1024, blk, 0, stream>>>(CP1, 8, conv1_b, A2b, nullptr, 262144, 1024, 1);

    // 9-11. conv2: M=64 K=4096, split-K x16 -> 256 blocks
    transpose_cast_kernel<<<16384, blk, 0, stream>>>(conv2_w, WTb);
    mgemm_kernel<<<dim3(1,16,16), blk, 0, stream>>>(
        A2b, WTb, nullptr, CP2, 1024, 4096, 256, -1, 0, 65536);
    epilogueB_kernel<<<256, blk, 0, stream>>>(CP2, 16, conv2_b, A3b, nullptr, 65536, 1024, 1);

    // 12-13. conv1d (M=1344, all 3 levels) + fc (M=64) in ONE launch:
    // grid.x 0..20 -> conv1d rows, grid.x==21 -> fc (A rows 1280.., B=Fb);
    // split-K x2 -> 704 blocks. Epilogue: VCb (bf16, remap) + GV (fp32).
    mgemm_kernel<<<dim3(22,16,2), blk, 0, stream>>>(
        Astack, C1b, Fb, CPcf, 1024, 1024, 512, 21, 1280, 1441792);
    epilogueCF_kernel<<<5632, blk, 0, stream>>>(CPcf, conv1d_b, fc_b, VCb, GV);

    // 14-15. attention logits: M=1344 N=1280 K=1024, split-K x2 -> 840 blocks
    mgemm_kernel<<<dim3(21,20,2), blk, 0, stream>>>(
        VCb, Wordsb, nullptr, CPat, 1280, 1024, 512, -1, 0, 1720320);
    epilogueB_kernel<<<6720, blk, 0, stream>>>(CPat, 2, nullptr, nullptr, Sb, 1720320, 1280, 0);

    // 16-22. glue
    rownorm_kernel<<<1344, blk, 0, stream>>>(VCb, VN, 1024);
    gram_kernel<<<dim3(64,100), blk, 0, stream>>>(Wordsb, GR);
    sim_kernel<<<21504, blk, 0, stream>>>(Sb, GR, VN, w_masks, SA);
    scores_kernel<<<16, blk, 0, stream>>>(SA, SC, out);
    l2normalize2_kernel<<<128, blk, 0, stream>>>(GV, GN, sentences, SN, 1024);
    gscore_kernel<<<1024, blk, 0, stream>>>(SN, GN, GS);
    loss_kernel<<<1, blk, 0, stream>>>(SC, GS, out);
}

// Round 5
// 258.383 us; speedup vs baseline: 2.8612x; 1.1603x over previous
//
#include <hip/hip_runtime.h>
#include <cmath>
#include <cstdint>

// B=64, T=64, W=20, D=1024, K=4, STRIDE=4 ; conv lengths 64->16->4->1 ; T_total=21

typedef __bf16 bf16_t;
typedef bf16_t bf16x8 __attribute__((ext_vector_type(8)));
typedef bf16_t bf16x4 __attribute__((ext_vector_type(4)));
typedef float  f32x4  __attribute__((ext_vector_type(4)));

__device__ __forceinline__ void gload_lds16(const void* g, void* l) {
    __builtin_amdgcn_global_load_lds(
        (const __attribute__((address_space(1))) void*)g,
        (__attribute__((address_space(3))) void*)l, 16, 0, 0);
}

// swizzled LDS offset (bf16 units) for logical (row, 8-elem chunk c):
// physical chunk = c ^ (row&7).  [R3: bank conflicts 6.29M -> 0]
__device__ __forceinline__ int swz(int r, int c) { return (r * 8 + (c ^ (r & 7))) * 8; }

// conv1d stack row remap: rows 0..1023 = level0 (b,16), 1024..1279 = level1 (b,4),
// 1280..1343 = level2 (b,1)  ->  VC row j*21 + t
__device__ __forceinline__ int remap1(int gm) {
    if (gm < 1024) return (gm >> 4) * 21 + (gm & 15);
    if (gm < 1280) { int g = gm - 1024; return (g >> 2) * 21 + 16 + (g & 3); }
    return (gm - 1280) * 21 + 20;
}

// ---------------- merged fp32 -> bf16 cast over up to 2 arrays ----------------
__global__ void cast_multi_kernel(
    const float* __restrict__ p0, bf16_t* __restrict__ q0, int n0,
    const float* __restrict__ p1, bf16_t* __restrict__ q1, int n1)
{
    int off = (blockIdx.x * 256 + threadIdx.x) * 4;
    const float* s; bf16_t* d;
    if (off < n0) { s = p0 + off; d = q0 + off; }
    else if ((off -= n0) < n1) { s = p1 + off; d = q1 + off; }
    else return;
    float4 v = *(const float4*)s;
    bf16x4 o = { (bf16_t)v.x, (bf16_t)v.y, (bf16_t)v.z, (bf16_t)v.w };
    *(bf16x4*)d = o;
}

// ---- weight transpose+cast: wt[o][k*1024+i] = (bf16) w[o][i*4+k] -------------
// R5: coalesced float4 reads (w[o][4i..4i+3]); per-k writes are wave-contiguous.
__global__ void transpose_cast_kernel(const float* __restrict__ w, bf16_t* __restrict__ wt) {
    int idx = blockIdx.x * 256 + threadIdx.x;   // 0 .. 1,048,576 = (o,i)
    int i = idx & 1023;
    int o = idx >> 10;
    float4 v = *(const float4*)(w + ((size_t)o << 12) + (i << 2));
    bf16_t* base = wt + ((size_t)o << 12) + i;
    base[0]    = (bf16_t)v.x;
    base[1024] = (bf16_t)v.y;
    base[2048] = (bf16_t)v.z;
    base[3072] = (bf16_t)v.w;
}

// ---------------- bf16 MFMA NT split-K GEMM -> fp32 partials ------------------
// 64x64 tile, BK=64, 4 waves (each 32x32 quadrant, 2x2 mfma_16x16x32), XOR-
// swizzled LDS, double-buffered global_load_lds staging. Split-K: slice z
// covers [z*Kchunk,(z+1)*Kchunk) -> CP + z*cpSlice (z-dim may be 1).
// fcTile: blockIdx.x at which A switches to row aRow0 and B switches to B2.
__global__ __launch_bounds__(256) void mgemm_kernel(
    const bf16_t* __restrict__ A, const bf16_t* __restrict__ B,
    const bf16_t* __restrict__ B2, float* __restrict__ CP,
    int N, int K, int Kchunk, int fcTile, int aRow0, int cpSlice)
{
    __shared__ __align__(16) bf16_t sA[2][4096];
    __shared__ __align__(16) bf16_t sB[2][4096];
    const int tid  = threadIdx.x;
    const int lane = tid & 63;
    const int wave = tid >> 6;
    const int bx = blockIdx.x;
    const int m0C = bx * 64;
    int m0A = m0C;
    const bf16_t* Buse = B;
    if (bx == fcTile) { m0A = aRow0; Buse = B2; }
    const int n0 = blockIdx.y * 64;
    const int k0 = blockIdx.z * Kchunk;

    const int sr = tid >> 3;              // staging row 0..31
    const int pc = tid & 7;               // physical chunk
    const int lc = pc ^ (sr & 7);         // logical chunk
    const bf16_t* Ag = A + (size_t)(m0A + sr) * K + lc * 8;
    const bf16_t* Bg = Buse + (size_t)(n0 + sr) * K + lc * 8;
    const size_t rowskip = (size_t)32 * K;

    const int wr = (wave >> 1) * 32;
    const int wc = (wave & 1) * 32;
    const int fm = lane & 15;
    const int cb = lane >> 4;

    int offA[2][2], offB[2][2];
    #pragma unroll
    for (int h = 0; h < 2; h++) {
        offA[h][0] = swz(wr +      fm, cb + h * 4);
        offA[h][1] = swz(wr + 16 + fm, cb + h * 4);
        offB[h][0] = swz(wc +      fm, cb + h * 4);
        offB[h][1] = swz(wc + 16 + fm, cb + h * 4);
    }

    f32x4 acc[2][2];
    #pragma unroll
    for (int a = 0; a < 2; a++)
        #pragma unroll
        for (int b = 0; b < 2; b++) acc[a][b] = (f32x4){0.f, 0.f, 0.f, 0.f};

    const int nIt = Kchunk >> 6;
    {   // prologue: stage tile 0 into buf 0
        const bf16_t* a = Ag + k0; const bf16_t* b = Bg + k0;
        gload_lds16(a,           &sA[0][tid * 8]);
        gload_lds16(a + rowskip, &sA[0][2048 + tid * 8]);
        gload_lds16(b,           &sB[0][tid * 8]);
        gload_lds16(b + rowskip, &sB[0][2048 + tid * 8]);
    }
    for (int it = 0; it < nIt; ++it) {
        const int buf = it & 1;
        __syncthreads();
        if (it + 1 < nIt) {
            const bf16_t* a = Ag + k0 + (it + 1) * 64;
            const bf16_t* b = Bg + k0 + (it + 1) * 64;
            bf16_t* dA = &sA[buf ^ 1][0];
            bf16_t* dB = &sB[buf ^ 1][0];
            gload_lds16(a,           dA + tid * 8);
            gload_lds16(a + rowskip, dA + 2048 + tid * 8);
            gload_lds16(b,           dB + tid * 8);
            gload_lds16(b + rowskip, dB + 2048 + tid * 8);
        }
        #pragma unroll
        for (int h = 0; h < 2; h++) {
            bf16x8 a0 = *(const bf16x8*)&sA[buf][offA[h][0]];
            bf16x8 a1 = *(const bf16x8*)&sA[buf][offA[h][1]];
            bf16x8 b0 = *(const bf16x8*)&sB[buf][offB[h][0]];
            bf16x8 b1 = *(const bf16x8*)&sB[buf][offB[h][1]];
            acc[0][0] = __builtin_amdgcn_mfma_f32_16x16x32_bf16(a0, b0, acc[0][0], 0, 0, 0);
            acc[0][1] = __builtin_amdgcn_mfma_f32_16x16x32_bf16(a0, b1, acc[0][1], 0, 0, 0);
            acc[1][0] = __builtin_amdgcn_mfma_f32_16x16x32_bf16(a1, b0, acc[1][0], 0, 0, 0);
            acc[1][1] = __builtin_amdgcn_mfma_f32_16x16x32_bf16(a1, b1, acc[1][1], 0, 0, 0);
        }
    }

    // C/D layout: col = lane&15, row = (lane>>4)*4 + reg   [verified m89/m91]
    float* Cz = CP + (size_t)blockIdx.z * cpSlice;
    #pragma unroll
    for (int im = 0; im < 2; im++)
        #pragma unroll
        for (int rr = 0; rr < 4; rr++) {
            int gm = m0C + wr + im * 16 + (lane >> 4) * 4 + rr;
            #pragma unroll
            for (int in_ = 0; in_ < 2; in_++) {
                int cg = n0 + wc + in_ * 16 + (lane & 15);
                Cz[(size_t)gm * N + cg] = acc[im][in_][rr];
            }
        }
}

// ------- split-K reduce + bias + relu -> bf16 and/or fp32 (identity remap) ----
__global__ void epilogueB_kernel(const float* __restrict__ CP_, int nz,
    const float* __restrict__ bias, bf16_t* __restrict__ D, float* __restrict__ D2,
    int MN, int N, int relu)
{
    int idx = blockIdx.x * 256 + threadIdx.x;
    if (idx >= MN) return;
    int n = idx % N;
    float s = 0.f;
    for (int z = 0; z < nz; z++) s += CP_[(size_t)z * MN + idx];
    if (bias) s += bias[n];
    if (relu) s = fmaxf(s, 0.f);
    if (D)  D[idx] = (bf16_t)s;
    if (D2) D2[idx] = s;
}

// ------- conv1d+fc combined epilogue: rows<1344 -> VCb (bf16, remap1),
//         rows>=1344 -> GV (fp32). 2 split-K slices. --------------------------
__global__ void epilogueCF_kernel(const float* __restrict__ CP_,
    const float* __restrict__ bias1, const float* __restrict__ biasf,
    bf16_t* __restrict__ VCb, float* __restrict__ GV)
{
    int idx = blockIdx.x * 256 + threadIdx.x;       // < 1441792
    int row = idx >> 10, n = idx & 1023;
    float s = CP_[idx] + CP_[idx + 1441792];
    if (row < 1344) VCb[(size_t)remap1(row) * 1024 + n] = (bf16_t)(s + bias1[n]);
    else            GV[(size_t)(row - 1344) * 1024 + n] = s + biasf[n];
}

// ---------------- per-row L2 norm of bf16 rows (value only) -------------------
__global__ void rownorm_kernel(const bf16_t* __restrict__ X, float* __restrict__ nrm, int D) {
    int r = blockIdx.x;
    const bf16_t* x = X + (size_t)r * D;
    float s = 0.f;
    for (int d = threadIdx.x; d < D; d += blockDim.x) { float v = (float)x[d]; s += v * v; }
    #pragma unroll
    for (int o = 32; o; o >>= 1) s += __shfl_xor(s, o, 64);
    __shared__ float red[4];
    if ((threadIdx.x & 63) == 0) red[threadIdx.x >> 6] = s;
    __syncthreads();
    if (threadIdx.x == 0) nrm[r] = sqrtf(red[0] + red[1] + red[2] + red[3]);
}

// ---------------- two-source per-row L2 normalize (fp32) ----------------------
__global__ void l2normalize2_kernel(const float* __restrict__ X0, float* __restrict__ Y0,
                                    const float* __restrict__ X1, float* __restrict__ Y1,
                                    int D) {
    int r = blockIdx.x & 63;
    const float* x = (blockIdx.x < 64 ? X0 : X1) + (size_t)r * D;
    float*       y = (blockIdx.x < 64 ? Y0 : Y1) + (size_t)r * D;
    float s = 0.f;
    for (int d = threadIdx.x; d < D; d += blockDim.x) { float v = x[d]; s += v * v; }
    #pragma unroll
    for (int o = 32; o; o >>= 1) s += __shfl_xor(s, o, 64);
    __shared__ float red[4];
    __shared__ float tot;
    if ((threadIdx.x & 63) == 0) red[threadIdx.x >> 6] = s;
    __syncthreads();
    if (threadIdx.x == 0) tot = 1.0f / fmaxf(sqrtf(red[0] + red[1] + red[2] + red[3]), 1e-8f);
    __syncthreads();
    float inv = tot;
    for (int d = threadIdx.x; d < D; d += blockDim.x) y[d] = x[d] * inv;
}

// ------- Gram from bf16 words: G[i][w][w'] = dot(Wb[i,w], Wb[i,w']) -----------
__global__ void gram_kernel(const bf16_t* __restrict__ Wb, float* __restrict__ G) {
    int i = blockIdx.x;                       // 64
    int wave = threadIdx.x >> 6;
    int lane = threadIdx.x & 63;
    int pair = blockIdx.y * 4 + wave;         // 0..399
    int w = pair / 20, w2 = pair % 20;
    const bf16_t* a = Wb + (((size_t)i * 20 + w)  << 10) + lane * 16;
    const bf16_t* b = Wb + (((size_t)i * 20 + w2) << 10) + lane * 16;
    bf16x8 a0 = *(const bf16x8*)a, a1 = *(const bf16x8*)(a + 8);
    bf16x8 b0 = *(const bf16x8*)b, b1 = *(const bf16x8*)(b + 8);
    float s = 0.f;
    #pragma unroll
    for (int e = 0; e < 8; e++)
        s += (float)a0[e] * (float)b0[e] + (float)a1[e] * (float)b1[e];
    #pragma unroll
    for (int o = 32; o; o >>= 1) s += __shfl_xor(s, o, 64);
    if (lane == 0) G[(size_t)i * 400 + pair] = s;
}

// ---------------- sim v2: one THREAD per (i, j*t) item ------------------------
// S2 layout [(i,w)][(j,t)] -> coalesced loads. G_i staged in LDS (broadcast
// reads). Softmax + quadratic form fully in registers, zero cross-lane ops.
__global__ __launch_bounds__(256) void sim_kernel(
    const float* __restrict__ S2, const float* __restrict__ G_,
    const float* __restrict__ VN_, const int* __restrict__ wmask,
    float* __restrict__ SA_)
{
    __shared__ float Gs[400];
    __shared__ float msk[20];
    const int i  = blockIdx.x;
    const int jt = blockIdx.y * 256 + threadIdx.x;   // 0..1535 (1344 used)
    for (int q = threadIdx.x; q < 400; q += 256) Gs[q] = G_[(size_t)i * 400 + q];
    if (threadIdx.x < 20) msk[threadIdx.x] = (wmask[i * 20 + threadIdx.x] != 0) ? 1.f : 0.f;
    __syncthreads();
    if (jt >= 1344) return;

    float s[20], p[20];
    float mx = -1e30f;
    #pragma unroll
    for (int w = 0; w < 20; w++) {
        s[w] = S2[(size_t)(i * 20 + w) * 1344 + jt];
        if (msk[w] != 0.f) mx = fmaxf(mx, s[w]);
    }
    float denom = 0.f, num = 0.f;
    #pragma unroll
    for (int w = 0; w < 20; w++) {
        p[w] = (msk[w] != 0.f) ? __expf(s[w] - mx) : 0.f;
        denom += p[w];
        num   += p[w] * s[w];
    }
    float quad = 0.f;
    #pragma unroll
    for (int w = 0; w < 20; w++) {
        float c = 0.f;
        #pragma unroll
        for (int w2 = 0; w2 < 20; w2++) c += Gs[w * 20 + w2] * p[w2];
        quad += p[w] * c;
    }
    float dot = num / denom;
    float vsn = sqrtf(fmaxf(quad, 0.f)) / denom;
    float sim = dot / (fmaxf(VN_[jt], 1e-8f) * fmaxf(vsn, 1e-8f));
    SA_[(size_t)i * 1344 + jt] = sim;
}

// ---------------- scores mean + positive_map ----------------------------------
__global__ void scores_kernel(const float* __restrict__ SA_, float* __restrict__ SC_,
                              float* __restrict__ out) {
    int idx = blockIdx.x * 256 + threadIdx.x;  // 4096 = i*64+j
    int i = idx >> 6, j = idx & 63;
    const float* row = SA_ + (size_t)idx * 21;
    float s = 0.f;
    #pragma unroll
    for (int t = 0; t < 21; t++) s += row[t];
    SC_[idx] = s * (1.0f / 21.0f);
    if (i == j) {
        #pragma unroll
        for (int t = 0; t < 21; t++) out[1 + i * 21 + t] = row[t];
    }
}

// ---------------- global-branch scores ----------------------------------------
__global__ void gscore_kernel(const float* __restrict__ SN_, const float* __restrict__ GN_,
                              float* __restrict__ GS_) {
    int item = blockIdx.x * 4 + (threadIdx.x >> 6);  // 4096
    int i = item >> 6, j = item & 63;
    int lane = threadIdx.x & 63;
    const float* a = SN_ + (size_t)i * 1024;
    const float* b = GN_ + (size_t)j * 1024;
    float s = 0.f;
    #pragma unroll
    for (int q = 0; q < 16; q++) { int d = lane + 64 * q; s += a[d] * b[d]; }
    #pragma unroll
    for (int o = 32; o; o >>= 1) s += __shfl_xor(s, o, 64);
    if (lane == 0) GS_[item] = s;
}

// ---------------- margin ranking loss -----------------------------------------
__global__ void loss_kernel(const float* __restrict__ SC_, const float* __restrict__ GS_,
                            float* __restrict__ out) {
    __shared__ float d1[64], d2[64], red[4];
    int tid = threadIdx.x;
    if (tid < 64) { d1[tid] = SC_[tid * 65]; d2[tid] = GS_[tid * 65]; }
    __syncthreads();
    float acc = 0.f;
    for (int idx = tid; idx < 4096; idx += 256) {
        int i = idx >> 6, j = idx & 63;
        if (i != j) {
            float s = SC_[idx];
            acc += fmaxf(0.2f + s - d1[i], 0.f) + fmaxf(0.2f + s - d1[j], 0.f);
            float g = GS_[idx];
            acc += fmaxf(0.2f + g - d2[i], 0.f) + fmaxf(0.2f + g - d2[j], 0.f);
        }
    }
    #pragma unroll
    for (int o = 32; o; o >>= 1) acc += __shfl_xor(acc, o, 64);
    if ((tid & 63) == 0) red[tid >> 6] = acc;
    __syncthreads();
    if (tid == 0) out[0] = (red[0] + red[1] + red[2] + red[3]) * (1.0f / 64.0f);
}

// ------------------------------------------------------------------------------
extern "C" void kernel_launch(void* const* d_in, const int* in_sizes, int n_in,
                              void* d_out, int out_size, void* d_ws, size_t ws_size,
                              hipStream_t stream)
{
    const float* video     = (const float*)d_in[0];
    const float* words     = (const float*)d_in[1];
    const int*   w_masks   = (const int*)  d_in[2];
    const float* sentences = (const float*)d_in[3];
    const float* conv0_w   = (const float*)d_in[4];
    const float* conv0_b   = (const float*)d_in[5];
    const float* conv1_w   = (const float*)d_in[6];
    const float* conv1_b   = (const float*)d_in[7];
    const float* conv2_w   = (const float*)d_in[8];
    const float* conv2_b   = (const float*)d_in[9];
    const float* conv1d_w  = (const float*)d_in[10];
    const float* conv1d_b  = (const float*)d_in[11];
    const float* fc_w      = (const float*)d_in[12];
    const float* fc_b      = (const float*)d_in[13];
    float* out = (float*)d_out;
    float* ws = (float*)d_ws;

    // ---- workspace (float units), total 8,323,072 f = 33.3 MB ----------------
    bf16_t* WTb    = (bf16_t*)(ws + 0);            // transposed weights (3x reuse)
    float*  S2     = ws + 0;                       // 1,720,320 f attn logits [(i,w)][(j,t)]
    float*  VN     = ws + 1720320;                 // 1,344
    float*  GR     = ws + 1721664;                 // 25,600
    float*  SA     = ws + 1747264;                 // 86,016
    float*  SC     = ws + 1833280;                 // 4,096
    float*  GV     = ws + 1837376;                 // 65,536
    float*  GN     = ws + 1902912;                 // 65,536
    float*  SN     = ws + 1968448;                 // 65,536
    float*  GS     = ws + 2033984;                 // 4,096 (ends 2,038,080 < 2M)
    bf16_t* Vb     = (bf16_t*)(ws + 2097152);      // 4,194,304 bf16
    float*  CP0    = ws + 4194304;                 // 2 x 1,048,576 f
    bf16_t* C1b    = (bf16_t*)(ws + 2097152);      // 1,048,576 bf16 (after conv0)
    bf16_t* Fb     = (bf16_t*)(ws + 2621440);      // 1,048,576 bf16
    float*  CP1    = ws + 4194304;                 // 8 x 262,144 f
    float*  CP2    = ws + 4194304;                 // 16 x 65,536 f
    float*  CPcf   = ws + 3145728;                 // 2 x 1,441,792 f (ends 6,029,312)
    bf16_t* Astack = (bf16_t*)(ws + 6291456);      // 1344x1024 bf16
    bf16_t* VCb    = (bf16_t*)(ws + 6979584);      // 1344x1024 bf16
    bf16_t* Wordsb = (bf16_t*)(ws + 7667712);      // 1,310,720 bf16 (ends 8,323,072)

    bf16_t* A2b = Astack + 1048576;   // rows 1024..1279
    bf16_t* A3b = Astack + 1310720;   // rows 1280..1343

    dim3 blk(256);

    // 1. cast video + words to bf16
    cast_multi_kernel<<<5376, blk, 0, stream>>>(video, Vb, 4194304, words, Wordsb, 1310720);

    // 2-4. conv0: M=1024 N=1024 K=4096, split-K x2 -> 512 blocks
    transpose_cast_kernel<<<4096, blk, 0, stream>>>(conv0_w, WTb);
    mgemm_kernel<<<dim3(16,16,2), blk, 0, stream>>>(
        Vb, WTb, nullptr, CP0, 1024, 4096, 2048, -1, 0, 1048576);
    epilogueB_kernel<<<4096, blk, 0, stream>>>(CP0, 2, conv0_b, Astack, nullptr, 1048576, 1024, 1);

    // 5. cast conv1d_w + fc_w (into pool space freed by Vb)
    cast_multi_kernel<<<2048, blk, 0, stream>>>(conv1d_w, C1b, 1048576, fc_w, Fb, 1048576);

    // 6-8. conv1: M=256 K=4096, split-K x8 -> 512 blocks
    transpose_cast_kernel<<<4096, blk, 0, stream>>>(conv1_w, WTb);
    mgemm_kernel<<<dim3(4,16,8), blk, 0, stream>>>(
        Astack, WTb, nullptr, CP1, 1024, 4096, 512, -1, 0, 262144);
    epilogueB_kernel<<<1024, blk, 0, stream>>>(CP1, 8, conv1_b, A2b, nullptr, 262144, 1024, 1);

    // 9-11. conv2: M=64 K=4096, split-K x16 -> 256 blocks
    transpose_cast_kernel<<<4096, blk, 0, stream>>>(conv2_w, WTb);
    mgemm_kernel<<<dim3(1,16,16), blk, 0, stream>>>(
        A2b, WTb, nullptr, CP2, 1024, 4096, 256, -1, 0, 65536);
    epilogueB_kernel<<<256, blk, 0, stream>>>(CP2, 16, conv2_b, A3b, nullptr, 65536, 1024, 1);

    // 12-13. conv1d (M=1344) + fc (M=64) in ONE launch; split-K x2 -> 704 blocks
    mgemm_kernel<<<dim3(22,16,2), blk, 0, stream>>>(
        Astack, C1b, Fb, CPcf, 1024, 1024, 512, 21, 1280, 1441792);
    epilogueCF_kernel<<<5632, blk, 0, stream>>>(CPcf, conv1d_b, fc_b, VCb, GV);

    // 14. attention logits TRANSPOSED: S2[(i,w)][(j,t)] = Wordsb . VCb^T
    //     M=1280 N=1344 K=1024, direct fp32 store, 420 blocks, no epilogue.
    mgemm_kernel<<<dim3(20,21,1), blk, 0, stream>>>(
        Wordsb, VCb, nullptr, S2, 1344, 1024, 1024, -1, 0, 0);

    // 15-21. glue
    rownorm_kernel<<<1344, blk, 0, stream>>>(VCb, VN, 1024);
    gram_kernel<<<dim3(64,100), blk, 0, stream>>>(Wordsb, GR);
    sim_kernel<<<dim3(64,6), blk, 0, stream>>>(S2, GR, VN, w_masks, SA);
    scores_kernel<<<16, blk, 0, stream>>>(SA, SC, out);
    l2normalize2_kernel<<<128, blk, 0, stream>>>(GV, GN, sentences, SN, 1024);
    gscore_kernel<<<1024, blk, 0, stream>>>(SN, GN, GS);
    loss_kernel<<<1, blk, 0, stream>>>(SC, GS, out);
}

// Round 6
// 242.809 us; speedup vs baseline: 3.0447x; 1.0641x over previous
//
#include <hip/hip_runtime.h>
#include <cmath>
#include <cstdint>

// B=64, T=64, W=20, D=1024, K=4, STRIDE=4 ; conv lengths 64->16->4->1 ; T_total=21

typedef __bf16 bf16_t;
typedef bf16_t bf16x8 __attribute__((ext_vector_type(8)));
typedef bf16_t bf16x4 __attribute__((ext_vector_type(4)));
typedef float  f32x4  __attribute__((ext_vector_type(4)));

__device__ __forceinline__ void gload_lds16(const void* g, void* l) {
    __builtin_amdgcn_global_load_lds(
        (const __attribute__((address_space(1))) void*)g,
        (__attribute__((address_space(3))) void*)l, 16, 0, 0);
}

// swizzled LDS offset (bf16 units): physical chunk = c ^ (row&7). [R3: conflicts->0]
__device__ __forceinline__ int swz(int r, int c) { return (r * 8 + (c ^ (r & 7))) * 8; }

// conv1d stack row remap -> VC row j*21 + t
__device__ __forceinline__ int remap1(int gm) {
    if (gm < 1024) return (gm >> 4) * 21 + (gm & 15);
    if (gm < 1280) { int g = gm - 1024; return (g >> 2) * 21 + 16 + (g & 3); }
    return (gm - 1280) * 21 + 20;
}

// ---------------- prep: 3 weight transposes + 4 casts in ONE kernel -----------
// blocks [0,4096) conv0_w->WT0 ; [4096,8192) conv1_w->WT1 ; [8192,12288) conv2_w->WT2
// [12288,16384) video->Vb ; [16384,17664) words->Wordsb ;
// [17664,18688) conv1d_w->C1b ; [18688,19712) fc_w->Fb
__global__ void prep_kernel(
    const float* __restrict__ c0w, const float* __restrict__ c1w,
    const float* __restrict__ c2w,
    bf16_t* __restrict__ WT0, bf16_t* __restrict__ WT1, bf16_t* __restrict__ WT2,
    const float* __restrict__ video, bf16_t* __restrict__ Vb,
    const float* __restrict__ words, bf16_t* __restrict__ Wordsb,
    const float* __restrict__ c1dw, bf16_t* __restrict__ C1b,
    const float* __restrict__ fcw, bf16_t* __restrict__ Fb)
{
    int bx = blockIdx.x;
    if (bx < 12288) {                       // transpose: wt[o][k*1024+i] = w[o][i*4+k]
        const float* w; bf16_t* wt;
        if (bx < 4096)      { w = c0w; wt = WT0; }
        else if (bx < 8192) { w = c1w; wt = WT1; bx -= 4096; }
        else                { w = c2w; wt = WT2; bx -= 8192; }
        int idx = bx * 256 + threadIdx.x;   // (o,i)
        int i = idx & 1023, o = idx >> 10;
        float4 v = *(const float4*)(w + ((size_t)o << 12) + (i << 2));
        bf16_t* base = wt + ((size_t)o << 12) + i;
        base[0]    = (bf16_t)v.x;
        base[1024] = (bf16_t)v.y;
        base[2048] = (bf16_t)v.z;
        base[3072] = (bf16_t)v.w;
    } else {                                // casts, 4 elems/thread
        const float* s; bf16_t* d;
        if (bx < 16384)      { s = video; d = Vb;     bx -= 12288; }
        else if (bx < 17664) { s = words; d = Wordsb; bx -= 16384; }
        else if (bx < 18688) { s = c1dw;  d = C1b;    bx -= 17664; }
        else                 { s = fcw;   d = Fb;     bx -= 18688; }
        int off = (bx * 256 + threadIdx.x) * 4;
        float4 v = *(const float4*)(s + off);
        bf16x4 o4 = { (bf16_t)v.x, (bf16_t)v.y, (bf16_t)v.z, (bf16_t)v.w };
        *(bf16x4*)(d + off) = o4;
    }
}

// ---------------- bf16 MFMA NT split-K GEMM -> fp32 partials ------------------
// 64x64 tile, BK=64, 4 waves (32x32 quadrants, 2x2 mfma_16x16x32), XOR-swizzled
// LDS, double-buffered global_load_lds. Slice z -> CP + z*cpSlice.
// fcTile: blockIdx.x at which A switches to row aRow0 and B switches to B2.
__global__ __launch_bounds__(256) void mgemm_kernel(
    const bf16_t* __restrict__ A, const bf16_t* __restrict__ B,
    const bf16_t* __restrict__ B2, float* __restrict__ CP,
    int N, int K, int Kchunk, int fcTile, int aRow0, int cpSlice)
{
    __shared__ __align__(16) bf16_t sA[2][4096];
    __shared__ __align__(16) bf16_t sB[2][4096];
    const int tid  = threadIdx.x;
    const int lane = tid & 63;
    const int wave = tid >> 6;
    const int bx = blockIdx.x;
    const int m0C = bx * 64;
    int m0A = m0C;
    const bf16_t* Buse = B;
    if (bx == fcTile) { m0A = aRow0; Buse = B2; }
    const int n0 = blockIdx.y * 64;
    const int k0 = blockIdx.z * Kchunk;

    const int sr = tid >> 3;
    const int pc = tid & 7;
    const int lc = pc ^ (sr & 7);
    const bf16_t* Ag = A + (size_t)(m0A + sr) * K + lc * 8;
    const bf16_t* Bg = Buse + (size_t)(n0 + sr) * K + lc * 8;
    const size_t rowskip = (size_t)32 * K;

    const int wr = (wave >> 1) * 32;
    const int wc = (wave & 1) * 32;
    const int fm = lane & 15;
    const int cb = lane >> 4;

    int offA[2][2], offB[2][2];
    #pragma unroll
    for (int h = 0; h < 2; h++) {
        offA[h][0] = swz(wr +      fm, cb + h * 4);
        offA[h][1] = swz(wr + 16 + fm, cb + h * 4);
        offB[h][0] = swz(wc +      fm, cb + h * 4);
        offB[h][1] = swz(wc + 16 + fm, cb + h * 4);
    }

    f32x4 acc[2][2];
    #pragma unroll
    for (int a = 0; a < 2; a++)
        #pragma unroll
        for (int b = 0; b < 2; b++) acc[a][b] = (f32x4){0.f, 0.f, 0.f, 0.f};

    const int nIt = Kchunk >> 6;
    {
        const bf16_t* a = Ag + k0; const bf16_t* b = Bg + k0;
        gload_lds16(a,           &sA[0][tid * 8]);
        gload_lds16(a + rowskip, &sA[0][2048 + tid * 8]);
        gload_lds16(b,           &sB[0][tid * 8]);
        gload_lds16(b + rowskip, &sB[0][2048 + tid * 8]);
    }
    for (int it = 0; it < nIt; ++it) {
        const int buf = it & 1;
        __syncthreads();
        if (it + 1 < nIt) {
            const bf16_t* a = Ag + k0 + (it + 1) * 64;
            const bf16_t* b = Bg + k0 + (it + 1) * 64;
            bf16_t* dA = &sA[buf ^ 1][0];
            bf16_t* dB = &sB[buf ^ 1][0];
            gload_lds16(a,           dA + tid * 8);
            gload_lds16(a + rowskip, dA + 2048 + tid * 8);
            gload_lds16(b,           dB + tid * 8);
            gload_lds16(b + rowskip, dB + 2048 + tid * 8);
        }
        #pragma unroll
        for (int h = 0; h < 2; h++) {
            bf16x8 a0 = *(const bf16x8*)&sA[buf][offA[h][0]];
            bf16x8 a1 = *(const bf16x8*)&sA[buf][offA[h][1]];
            bf16x8 b0 = *(const bf16x8*)&sB[buf][offB[h][0]];
            bf16x8 b1 = *(const bf16x8*)&sB[buf][offB[h][1]];
            acc[0][0] = __builtin_amdgcn_mfma_f32_16x16x32_bf16(a0, b0, acc[0][0], 0, 0, 0);
            acc[0][1] = __builtin_amdgcn_mfma_f32_16x16x32_bf16(a0, b1, acc[0][1], 0, 0, 0);
            acc[1][0] = __builtin_amdgcn_mfma_f32_16x16x32_bf16(a1, b0, acc[1][0], 0, 0, 0);
            acc[1][1] = __builtin_amdgcn_mfma_f32_16x16x32_bf16(a1, b1, acc[1][1], 0, 0, 0);
        }
    }

    // C/D layout: col = lane&15, row = (lane>>4)*4 + reg   [verified m89/m91]
    float* Cz = CP + (size_t)blockIdx.z * cpSlice;
    #pragma unroll
    for (int im = 0; im < 2; im++)
        #pragma unroll
        for (int rr = 0; rr < 4; rr++) {
            int gm = m0C + wr + im * 16 + (lane >> 4) * 4 + rr;
            #pragma unroll
            for (int in_ = 0; in_ < 2; in_++) {
                int cg = n0 + wc + in_ * 16 + (lane & 15);
                Cz[(size_t)gm * N + cg] = acc[im][in_][rr];
            }
        }
}

// ------- split-K reduce + bias + relu -> bf16 -------------------------------
__global__ void epilogueB_kernel(const float* __restrict__ CP_, int nz,
    const float* __restrict__ bias, bf16_t* __restrict__ D, int MN, int N, int relu)
{
    int idx = blockIdx.x * 256 + threadIdx.x;
    if (idx >= MN) return;
    int n = idx % N;
    float s = 0.f;
    for (int z = 0; z < nz; z++) s += CP_[(size_t)z * MN + idx];
    if (bias) s += bias[n];
    if (relu) s = fmaxf(s, 0.f);
    D[idx] = (bf16_t)s;
}

// ------- conv1d+fc combined epilogue (4 split-K slices): rows<1344 -> VCb
//         (bf16, remap1), rows>=1344 -> GV (fp32) -----------------------------
__global__ void epilogueCF_kernel(const float* __restrict__ CP_,
    const float* __restrict__ bias1, const float* __restrict__ biasf,
    bf16_t* __restrict__ VCb, float* __restrict__ GV)
{
    int idx = blockIdx.x * 256 + threadIdx.x;       // < 1441792
    int row = idx >> 10, n = idx & 1023;
    float s = CP_[idx] + CP_[idx + 1441792] + CP_[idx + 2 * 1441792] + CP_[idx + 3 * 1441792];
    if (row < 1344) VCb[(size_t)remap1(row) * 1024 + n] = (bf16_t)(s + bias1[n]);
    else            GV[(size_t)(row - 1344) * 1024 + n] = s + biasf[n];
}

// ------- fused rownorm (blocks <1344) + gram (blocks >=1344) ------------------
__global__ void normgram_kernel(const bf16_t* __restrict__ VCb, float* __restrict__ VN,
                                const bf16_t* __restrict__ Wb, float* __restrict__ G)
{
    int bx = blockIdx.x;
    if (bx < 1344) {                       // ||VC row||
        const bf16_t* x = VCb + ((size_t)bx << 10);
        float s = 0.f;
        for (int d = threadIdx.x; d < 1024; d += 256) { float v = (float)x[d]; s += v * v; }
        #pragma unroll
        for (int o = 32; o; o >>= 1) s += __shfl_xor(s, o, 64);
        __shared__ float red[4];
        if ((threadIdx.x & 63) == 0) red[threadIdx.x >> 6] = s;
        __syncthreads();
        if (threadIdx.x == 0) VN[bx] = sqrtf(red[0] + red[1] + red[2] + red[3]);
    } else {                               // Gram: one wave per (w,w') pair
        int g = bx - 1344;                 // 0..6399
        int i = g / 100, piece = g % 100;
        int wave = threadIdx.x >> 6, lane = threadIdx.x & 63;
        int pair = piece * 4 + wave;       // 0..399
        int w = pair / 20, w2 = pair % 20;
        const bf16_t* a = Wb + (((size_t)i * 20 + w)  << 10) + lane * 16;
        const bf16_t* b = Wb + (((size_t)i * 20 + w2) << 10) + lane * 16;
        bf16x8 a0 = *(const bf16x8*)a, a1 = *(const bf16x8*)(a + 8);
        bf16x8 b0 = *(const bf16x8*)b, b1 = *(const bf16x8*)(b + 8);
        float s = 0.f;
        #pragma unroll
        for (int e = 0; e < 8; e++)
            s += (float)a0[e] * (float)b0[e] + (float)a1[e] * (float)b1[e];
        #pragma unroll
        for (int o = 32; o; o >>= 1) s += __shfl_xor(s, o, 64);
        if (lane == 0) G[(size_t)i * 400 + pair] = s;
    }
}

// ---------------- sim: one THREAD per (i, jt); reads 2 split-K slices ---------
__global__ __launch_bounds__(256) void sim_kernel(
    const float* __restrict__ CPat, const float* __restrict__ G_,
    const float* __restrict__ VN_, const int* __restrict__ wmask,
    float* __restrict__ SA_)
{
    __shared__ float Gs[400];
    __shared__ float msk[20];
    const int i  = blockIdx.x;
    const int jt = blockIdx.y * 256 + threadIdx.x;   // 0..1535 (1344 used)
    for (int q = threadIdx.x; q < 400; q += 256) Gs[q] = G_[(size_t)i * 400 + q];
    if (threadIdx.x < 20) msk[threadIdx.x] = (wmask[i * 20 + threadIdx.x] != 0) ? 1.f : 0.f;
    __syncthreads();
    if (jt >= 1344) return;

    float s[20], p[20];
    float mx = -1e30f;
    #pragma unroll
    for (int w = 0; w < 20; w++) {
        size_t q = (size_t)(i * 20 + w) * 1344 + jt;
        s[w] = CPat[q] + CPat[q + 1720320];
        if (msk[w] != 0.f) mx = fmaxf(mx, s[w]);
    }
    float denom = 0.f, num = 0.f;
    #pragma unroll
    for (int w = 0; w < 20; w++) {
        p[w] = (msk[w] != 0.f) ? __expf(s[w] - mx) : 0.f;
        denom += p[w];
        num   += p[w] * s[w];
    }
    float quad = 0.f;
    #pragma unroll
    for (int w = 0; w < 20; w++) {
        float c = 0.f;
        #pragma unroll
        for (int w2 = 0; w2 < 20; w2++) c += Gs[w * 20 + w2] * p[w2];
        quad += p[w] * c;
    }
    float dot = num / denom;
    float vsn = sqrtf(fmaxf(quad, 0.f)) / denom;
    float sim = dot / (fmaxf(VN_[jt], 1e-8f) * fmaxf(vsn, 1e-8f));
    SA_[(size_t)i * 1344 + jt] = sim;
}

// ------- fused scores+positive_map (blocks <16) + l2normalize x2 (>=16) -------
__global__ void scores_l2_kernel(const float* __restrict__ SA_, float* __restrict__ SC_,
                                 float* __restrict__ out,
                                 const float* __restrict__ GV, float* __restrict__ GN,
                                 const float* __restrict__ sent, float* __restrict__ SN)
{
    int bx = blockIdx.x;
    if (bx < 16) {
        int idx = bx * 256 + threadIdx.x;  // 4096 = i*64+j
        int i = idx >> 6, j = idx & 63;
        const float* row = SA_ + (size_t)idx * 21;
        float s = 0.f;
        #pragma unroll
        for (int t = 0; t < 21; t++) s += row[t];
        SC_[idx] = s * (1.0f / 21.0f);
        if (i == j) {
            #pragma unroll
            for (int t = 0; t < 21; t++) out[1 + i * 21 + t] = row[t];
        }
    } else {
        int b2 = bx - 16;                  // 0..127
        int r = b2 & 63;
        const float* x = (b2 < 64 ? GV : sent) + ((size_t)r << 10);
        float*       y = (b2 < 64 ? GN : SN)   + ((size_t)r << 10);
        float s = 0.f;
        for (int d = threadIdx.x; d < 1024; d += 256) { float v = x[d]; s += v * v; }
        #pragma unroll
        for (int o = 32; o; o >>= 1) s += __shfl_xor(s, o, 64);
        __shared__ float red[4];
        __shared__ float tot;
        if ((threadIdx.x & 63) == 0) red[threadIdx.x >> 6] = s;
        __syncthreads();
        if (threadIdx.x == 0) tot = 1.0f / fmaxf(sqrtf(red[0] + red[1] + red[2] + red[3]), 1e-8f);
        __syncthreads();
        float inv = tot;
        for (int d = threadIdx.x; d < 1024; d += 256) y[d] = x[d] * inv;
    }
}

// ---------------- global-branch scores ----------------------------------------
__global__ void gscore_kernel(const float* __restrict__ SN_, const float* __restrict__ GN_,
                              float* __restrict__ GS_) {
    int item = blockIdx.x * 4 + (threadIdx.x >> 6);  // 4096
    int i = item >> 6, j = item & 63;
    int lane = threadIdx.x & 63;
    const float* a = SN_ + (size_t)i * 1024;
    const float* b = GN_ + (size_t)j * 1024;
    float s = 0.f;
    #pragma unroll
    for (int q = 0; q < 16; q++) { int d = lane + 64 * q; s += a[d] * b[d]; }
    #pragma unroll
    for (int o = 32; o; o >>= 1) s += __shfl_xor(s, o, 64);
    if (lane == 0) GS_[item] = s;
}

// ---------------- margin ranking loss -----------------------------------------
__global__ void loss_kernel(const float* __restrict__ SC_, const float* __restrict__ GS_,
                            float* __restrict__ out) {
    __shared__ float d1[64], d2[64], red[4];
    int tid = threadIdx.x;
    if (tid < 64) { d1[tid] = SC_[tid * 65]; d2[tid] = GS_[tid * 65]; }
    __syncthreads();
    float acc = 0.f;
    for (int idx = tid; idx < 4096; idx += 256) {
        int i = idx >> 6, j = idx & 63;
        if (i != j) {
            float s = SC_[idx];
            acc += fmaxf(0.2f + s - d1[i], 0.f) + fmaxf(0.2f + s - d1[j], 0.f);
            float g = GS_[idx];
            acc += fmaxf(0.2f + g - d2[i], 0.f) + fmaxf(0.2f + g - d2[j], 0.f);
        }
    }
    #pragma unroll
    for (int o = 32; o; o >>= 1) acc += __shfl_xor(acc, o, 64);
    if ((tid & 63) == 0) red[tid >> 6] = acc;
    __syncthreads();
    if (tid == 0) out[0] = (red[0] + red[1] + red[2] + red[3]) * (1.0f / 64.0f);
}

// ------------------------------------------------------------------------------
extern "C" void kernel_launch(void* const* d_in, const int* in_sizes, int n_in,
                              void* d_out, int out_size, void* d_ws, size_t ws_size,
                              hipStream_t stream)
{
    const float* video     = (const float*)d_in[0];
    const float* words     = (const float*)d_in[1];
    const int*   w_masks   = (const int*)  d_in[2];
    const float* sentences = (const float*)d_in[3];
    const float* conv0_w   = (const float*)d_in[4];
    const float* conv0_b   = (const float*)d_in[5];
    const float* conv1_w   = (const float*)d_in[6];
    const float* conv1_b   = (const float*)d_in[7];
    const float* conv2_w   = (const float*)d_in[8];
    const float* conv2_b   = (const float*)d_in[9];
    const float* conv1d_w  = (const float*)d_in[10];
    const float* conv1d_b  = (const float*)d_in[11];
    const float* fc_w      = (const float*)d_in[12];
    const float* fc_b      = (const float*)d_in[13];
    float* out = (float*)d_out;
    float* ws = (float*)d_ws;

    // ---- flat workspace (float units), ~31.4M f = 126 MB, no aliasing --------
    bf16_t* WT0    = (bf16_t*)(ws + 0);            // 1024x4096 bf16
    bf16_t* WT1    = (bf16_t*)(ws + 2097152);
    bf16_t* WT2    = (bf16_t*)(ws + 4194304);
    bf16_t* Vb     = (bf16_t*)(ws + 6291456);      // 4,194,304 bf16
    bf16_t* Wordsb = (bf16_t*)(ws + 8388608);      // 1,310,720 bf16
    bf16_t* C1b    = (bf16_t*)(ws + 9043968);      // 1,048,576 bf16
    bf16_t* Fb     = (bf16_t*)(ws + 9568256);      // 1,048,576 bf16
    bf16_t* Astack = (bf16_t*)(ws + 10092544);     // 1344x1024 bf16
    bf16_t* VCb    = (bf16_t*)(ws + 10780672);     // 1344x1024 bf16
    float*  CP0    = ws + 11468800;                // 4 x 1,048,576 f
    float*  CP1    = ws + 15663104;                // 16 x 262,144 f
    float*  CP2    = ws + 19857408;                // 32 x 65,536 f
    float*  CPcf   = ws + 21954560;                // 4 x 1,441,792 f
    float*  CPat   = ws + 27721728;                // 2 x 1,720,320 f
    float*  VN     = ws + 31162368;                // 1,344
    float*  GR     = ws + 31163712;                // 25,600
    float*  SA     = ws + 31189312;                // 86,016
    float*  SC     = ws + 31275328;                // 4,096
    float*  GV     = ws + 31279424;                // 65,536
    float*  GN     = ws + 31344960;                // 65,536
    float*  SN     = ws + 31410496;                // 65,536
    // GS          = ws + 31476032;                // 4,096 (ends 31,480,128)
    float*  GS     = ws + 31476032;

    bf16_t* A2b = Astack + 1048576;   // rows 1024..1279
    bf16_t* A3b = Astack + 1310720;   // rows 1280..1343

    dim3 blk(256);

    // 1. prep: all transposes + casts
    prep_kernel<<<19712, blk, 0, stream>>>(
        conv0_w, conv1_w, conv2_w, WT0, WT1, WT2,
        video, Vb, words, Wordsb, conv1d_w, C1b, fc_w, Fb);

    // 2-3. conv0: M=1024 N=1024 K=4096, split-K x4 -> 1024 blocks (4/CU)
    mgemm_kernel<<<dim3(16,16,4), blk, 0, stream>>>(
        Vb, WT0, nullptr, CP0, 1024, 4096, 1024, -1, 0, 1048576);
    epilogueB_kernel<<<4096, blk, 0, stream>>>(CP0, 4, conv0_b, Astack, 1048576, 1024, 1);

    // 4-5. conv1: M=256 K=4096, split-K x16 -> 1024 blocks
    mgemm_kernel<<<dim3(4,16,16), blk, 0, stream>>>(
        Astack, WT1, nullptr, CP1, 1024, 4096, 256, -1, 0, 262144);
    epilogueB_kernel<<<1024, blk, 0, stream>>>(CP1, 16, conv1_b, A2b, 262144, 1024, 1);

    // 6-7. conv2: M=64 K=4096, split-K x32 -> 512 blocks
    mgemm_kernel<<<dim3(1,16,32), blk, 0, stream>>>(
        A2b, WT2, nullptr, CP2, 1024, 4096, 128, -1, 0, 65536);
    epilogueB_kernel<<<256, blk, 0, stream>>>(CP2, 32, conv2_b, A3b, 65536, 1024, 1);

    // 8-9. conv1d (M=1344) + fc (M=64) in ONE launch; split-K x4 -> 1408 blocks
    mgemm_kernel<<<dim3(22,16,4), blk, 0, stream>>>(
        Astack, C1b, Fb, CPcf, 1024, 1024, 256, 21, 1280, 1441792);
    epilogueCF_kernel<<<5632, blk, 0, stream>>>(CPcf, conv1d_b, fc_b, VCb, GV);

    // 10. attention logits TRANSPOSED, split-K x2 -> 840 blocks:
    //     CPat[z][(i,w)][(j,t)] partial = Wordsb . VCb^T ; sim sums the slices.
    mgemm_kernel<<<dim3(20,21,2), blk, 0, stream>>>(
        Wordsb, VCb, nullptr, CPat, 1344, 1024, 512, -1, 0, 1720320);

    // 11-15. glue
    normgram_kernel<<<7744, blk, 0, stream>>>(VCb, VN, Wordsb, GR);
    sim_kernel<<<dim3(64,6), blk, 0, stream>>>(CPat, GR, VN, w_masks, SA);
    scores_l2_kernel<<<144, blk, 0, stream>>>(SA, SC, out, GV, GN, sentences, SN);
    gscore_kernel<<<1024, blk, 0, stream>>>(SN, GN, GS);
    loss_kernel<<<1, blk, 0, stream>>>(SC, GS, out);
}